// Round 1
// baseline (6413.294 us; speedup 1.0000x reference)
//
#include <hip/hip_runtime.h>
#include <math.h>

#define DMODEL 512
#define DINNER 1024
#define DSTATE 16
#define DTRANK 32
#define NLAYERS 6
#define BB 2
#define LT 512
#define LS 512

// ---------------- epilogues ----------------
// 0=none, 1=bias+relu, 2=bias, 3=bias+softplus
template<int EPI>
__device__ __forceinline__ float epi_apply(float acc, float b) {
  if (EPI == 1) { float v = acc + b; return v > 0.f ? v : 0.f; }
  if (EPI == 2) { return acc + b; }
  if (EPI == 3) { float v = acc + b; return fmaxf(v, 0.f) + log1pf(__expf(-fabsf(v))); }
  return acc;
}

// ---------------- embedding + sinusoidal PE ----------------
__global__ __launch_bounds__(256) void embed_kernel(const int* __restrict__ tgt,
    const float* __restrict__ emb, float* __restrict__ X) {
  int i = blockIdx.x * 256 + threadIdx.x;     // over BB*LT*DMODEL
  int d = i & (DMODEL - 1);
  int bt = i >> 9;
  int t = bt & (LT - 1);
  int tok = tgt[bt];
  float div = __expf((float)(d & ~1) * (-9.210340371976184f / (float)DMODEL));
  float ang = (float)t * div;
  float pe = (d & 1) ? cosf(ang) : sinf(ang);
  X[i] = emb[(size_t)tok * DMODEL + d] * 22.627416997969522f + pe;
}

// ---------------- concat [src, x] along time ----------------
__global__ __launch_bounds__(256) void concat_kernel(const float* __restrict__ src,
    const float* __restrict__ X, float* __restrict__ CAT) {
  int i = blockIdx.x * 256 + threadIdx.x;     // float4 index over BB*1024*512/4
  int c = i & 127;
  int r = i >> 7;
  int l = r & 1023;
  int b = r >> 10;
  const float* s = (l < LS) ? (src + ((size_t)b * LS + l) * DMODEL)
                            : (X + ((size_t)b * LT + (l - LS)) * DMODEL);
  ((float4*)CAT)[(size_t)r * 128 + c] = ((const float4*)s)[c];
}

// ---------------- GEMM: C[M,N] = A[M,K] * B[N,K]^T, 128x128 tile ----------------
template<int EPI>
__global__ __launch_bounds__(256) void gemm128(
    const float* __restrict__ A, const float* __restrict__ Bw,
    const float* __restrict__ bias, float* __restrict__ C,
    int M, int N, int K, int lda) {
  __shared__ __align__(16) float As[8][128];
  __shared__ __align__(16) float Bs[8][128];
  const int tid = threadIdx.x;
  const int bn = blockIdx.x * 128;
  const int bm = blockIdx.y * 128;
  const int tx = tid & 15;
  const int ty = tid >> 4;
  const int lrow = tid >> 1;
  const int lk = (tid & 1) * 4;
  float acc[8][8];
#pragma unroll
  for (int i = 0; i < 8; ++i)
#pragma unroll
    for (int j = 0; j < 8; ++j) acc[i][j] = 0.f;

  for (int k0 = 0; k0 < K; k0 += 8) {
    float4 av = *(const float4*)(A + (size_t)(bm + lrow) * lda + k0 + lk);
    float4 bv = *(const float4*)(Bw + (size_t)(bn + lrow) * K + k0 + lk);
    __syncthreads();
    As[lk + 0][lrow] = av.x; As[lk + 1][lrow] = av.y;
    As[lk + 2][lrow] = av.z; As[lk + 3][lrow] = av.w;
    Bs[lk + 0][lrow] = bv.x; Bs[lk + 1][lrow] = bv.y;
    Bs[lk + 2][lrow] = bv.z; Bs[lk + 3][lrow] = bv.w;
    __syncthreads();
#pragma unroll
    for (int kk = 0; kk < 8; ++kk) {
      float4 a0 = *(const float4*)&As[kk][ty * 8];
      float4 a1 = *(const float4*)&As[kk][ty * 8 + 4];
      float4 b0 = *(const float4*)&Bs[kk][tx * 8];
      float4 b1 = *(const float4*)&Bs[kk][tx * 8 + 4];
      float ar[8] = {a0.x, a0.y, a0.z, a0.w, a1.x, a1.y, a1.z, a1.w};
      float br[8] = {b0.x, b0.y, b0.z, b0.w, b1.x, b1.y, b1.z, b1.w};
#pragma unroll
      for (int i = 0; i < 8; ++i)
#pragma unroll
        for (int j = 0; j < 8; ++j)
          acc[i][j] = fmaf(ar[i], br[j], acc[i][j]);
    }
  }
  float bv8[8];
  if (EPI != 0) {
#pragma unroll
    for (int j = 0; j < 8; ++j) bv8[j] = bias[bn + tx * 8 + j];
  } else {
#pragma unroll
    for (int j = 0; j < 8; ++j) bv8[j] = 0.f;
  }
#pragma unroll
  for (int i = 0; i < 8; ++i) {
    size_t crow = (size_t)(bm + ty * 8 + i) * N + bn + tx * 8;
#pragma unroll
    for (int j = 0; j < 8; ++j)
      C[crow + j] = epi_apply<EPI>(acc[i][j], bv8[j]);
  }
}

// ---------------- GEMM: 64x64 tile, 4x4 microtile ----------------
template<int EPI>
__global__ __launch_bounds__(256) void gemm64(
    const float* __restrict__ A, const float* __restrict__ Bw,
    const float* __restrict__ bias, float* __restrict__ C,
    int M, int N, int K, int lda) {
  __shared__ __align__(16) float As[16][64];
  __shared__ __align__(16) float Bs[16][64];
  const int tid = threadIdx.x;
  const int bn = blockIdx.x * 64;
  const int bm = blockIdx.y * 64;
  const int tx = tid & 15;
  const int ty = tid >> 4;
  const int lrow = tid >> 2;
  const int lk = (tid & 3) * 4;
  float acc[4][4];
#pragma unroll
  for (int i = 0; i < 4; ++i)
#pragma unroll
    for (int j = 0; j < 4; ++j) acc[i][j] = 0.f;

  for (int k0 = 0; k0 < K; k0 += 16) {
    float4 av = *(const float4*)(A + (size_t)(bm + lrow) * lda + k0 + lk);
    float4 bv = *(const float4*)(Bw + (size_t)(bn + lrow) * K + k0 + lk);
    __syncthreads();
    As[lk + 0][lrow] = av.x; As[lk + 1][lrow] = av.y;
    As[lk + 2][lrow] = av.z; As[lk + 3][lrow] = av.w;
    Bs[lk + 0][lrow] = bv.x; Bs[lk + 1][lrow] = bv.y;
    Bs[lk + 2][lrow] = bv.z; Bs[lk + 3][lrow] = bv.w;
    __syncthreads();
#pragma unroll
    for (int kk = 0; kk < 16; ++kk) {
      float4 a = *(const float4*)&As[kk][ty * 4];
      float4 b = *(const float4*)&Bs[kk][tx * 4];
      float ar[4] = {a.x, a.y, a.z, a.w};
      float br[4] = {b.x, b.y, b.z, b.w};
#pragma unroll
      for (int i = 0; i < 4; ++i)
#pragma unroll
        for (int j = 0; j < 4; ++j)
          acc[i][j] = fmaf(ar[i], br[j], acc[i][j]);
    }
  }
  float bv4[4];
  if (EPI != 0) {
#pragma unroll
    for (int j = 0; j < 4; ++j) bv4[j] = bias[bn + tx * 4 + j];
  } else {
#pragma unroll
    for (int j = 0; j < 4; ++j) bv4[j] = 0.f;
  }
#pragma unroll
  for (int i = 0; i < 4; ++i) {
    size_t crow = (size_t)(bm + ty * 4 + i) * N + bn + tx * 4;
#pragma unroll
    for (int j = 0; j < 4; ++j)
      C[crow + j] = epi_apply<EPI>(acc[i][j], bv4[j]);
  }
}

// ---------------- GEMM 64x64 with split-K (partials, no epilogue) ----------------
__global__ __launch_bounds__(256) void gemm64_split(
    const float* __restrict__ A, const float* __restrict__ Bw,
    float* __restrict__ P, int M, int N, int K, int lda) {
  __shared__ __align__(16) float As[16][64];
  __shared__ __align__(16) float Bs[16][64];
  const int tid = threadIdx.x;
  const int bn = blockIdx.x * 64;
  const int bm = blockIdx.y * 64;
  const int nz = gridDim.z;
  const int kc = K / nz;
  const int kbeg = blockIdx.z * kc;
  const int tx = tid & 15;
  const int ty = tid >> 4;
  const int lrow = tid >> 2;
  const int lk = (tid & 3) * 4;
  float acc[4][4];
#pragma unroll
  for (int i = 0; i < 4; ++i)
#pragma unroll
    for (int j = 0; j < 4; ++j) acc[i][j] = 0.f;

  for (int k0 = kbeg; k0 < kbeg + kc; k0 += 16) {
    float4 av = *(const float4*)(A + (size_t)(bm + lrow) * lda + k0 + lk);
    float4 bv = *(const float4*)(Bw + (size_t)(bn + lrow) * K + k0 + lk);
    __syncthreads();
    As[lk + 0][lrow] = av.x; As[lk + 1][lrow] = av.y;
    As[lk + 2][lrow] = av.z; As[lk + 3][lrow] = av.w;
    Bs[lk + 0][lrow] = bv.x; Bs[lk + 1][lrow] = bv.y;
    Bs[lk + 2][lrow] = bv.z; Bs[lk + 3][lrow] = bv.w;
    __syncthreads();
#pragma unroll
    for (int kk = 0; kk < 16; ++kk) {
      float4 a = *(const float4*)&As[kk][ty * 4];
      float4 b = *(const float4*)&Bs[kk][tx * 4];
      float ar[4] = {a.x, a.y, a.z, a.w};
      float br[4] = {b.x, b.y, b.z, b.w};
#pragma unroll
      for (int i = 0; i < 4; ++i)
#pragma unroll
        for (int j = 0; j < 4; ++j)
          acc[i][j] = fmaf(ar[i], br[j], acc[i][j]);
    }
  }
  float* Pz = P + (size_t)blockIdx.z * M * N;
#pragma unroll
  for (int i = 0; i < 4; ++i) {
    size_t crow = (size_t)(bm + ty * 4 + i) * N + bn + tx * 4;
#pragma unroll
    for (int j = 0; j < 4; ++j)
      Pz[crow + j] = acc[i][j];
  }
}

__global__ __launch_bounds__(256) void reduce_sum_kernel(const float* __restrict__ P,
    float* __restrict__ C, int total, int nz) {
  int i = blockIdx.x * 256 + threadIdx.x;
  if (i >= total) return;
  float s = 0.f;
  for (int z = 0; z < nz; ++z) s += P[(size_t)z * total + i];
  C[i] = s;
}

// ---------------- causal depthwise conv (k=4) + bias + silu ----------------
__global__ __launch_bounds__(256) void conv_silu_kernel(
    const float* __restrict__ xz, const float* __restrict__ w,
    const float* __restrict__ bias, float* __restrict__ out, int L) {
  int idx = blockIdx.x * 256 + threadIdx.x;   // over BB*L*DINNER
  int d = idx & (DINNER - 1);
  int bt = idx >> 10;
  int b = bt / L;
  int t = bt - b * L;
  const float* col = xz + ((size_t)b * L) * (2 * DINNER) + d;
  float acc = bias[d];
#pragma unroll
  for (int k = 0; k < 4; ++k) {
    int tt = t - 3 + k;
    if (tt >= 0) acc = fmaf(col[(size_t)tt * (2 * DINNER)], w[d * 4 + k], acc);
  }
  float sig = 1.f / (1.f + __expf(-acc));
  out[idx] = acc * sig;
}

// ---------------- selective scan + gating ----------------
// lane n of each 16-lane group owns state (b,d,n); y = sum_n h*C via shfl.
__global__ __launch_bounds__(256) void scan_kernel(
    const float* __restrict__ dt, const float* __restrict__ dbl,
    const float* __restrict__ u, const float* __restrict__ xz,
    const float* __restrict__ Alog, const float* __restrict__ Dsk,
    float* __restrict__ ys, int L) {
  int tid = threadIdx.x;
  int g = tid >> 4, n = tid & 15;
  int chan = blockIdx.x * 16 + g;    // 0..2047
  int b = chan >> 10, d = chan & 1023;
  float A = -__expf(Alog[d * DSTATE + n]);
  float Dv = Dsk[d];
  const float* dtp = dt + ((size_t)b * L) * DINNER + d;
  const float* up  = u  + ((size_t)b * L) * DINNER + d;
  const float* zp  = xz + ((size_t)b * L) * (2 * DINNER) + DINNER + d;
  const float* Bp  = dbl + ((size_t)b * L) * 64 + DTRANK + n;
  const float* Cp  = Bp + DSTATE;
  float* yp = ys + ((size_t)b * L) * DINNER + d;
  float h = 0.f;
  float dt0 = dtp[0], u0 = up[0], B0 = Bp[0], C0 = Cp[0], z0 = zp[0];
  for (int t = 0; t < L; ++t) {
    int t1 = (t + 1 < L) ? t + 1 : t;
    float dt1 = dtp[(size_t)t1 * DINNER];
    float u1  = up[(size_t)t1 * DINNER];
    float B1  = Bp[(size_t)t1 * 64];
    float C1  = Cp[(size_t)t1 * 64];
    float z1  = zp[(size_t)t1 * (2 * DINNER)];
    float dA = __expf(dt0 * A);
    h = fmaf(dA, h, dt0 * u0 * B0);
    float r = h * C0;
    r += __shfl_xor(r, 1);
    r += __shfl_xor(r, 2);
    r += __shfl_xor(r, 4);
    r += __shfl_xor(r, 8);
    if (n == 0) {
      float sig = 1.f / (1.f + __expf(-z0));
      yp[(size_t)t * DINNER] = (r + u0 * Dv) * (z0 * sig);
    }
    dt0 = dt1; u0 = u1; B0 = B1; C0 = C1; z0 = z1;
  }
}

// ---------------- LayerNorm (optional residual add), row = 512 ----------------
__global__ __launch_bounds__(64) void ln_kernel(
    const float* __restrict__ res, const float* __restrict__ add,
    long long add_bstride, long long add_off,
    const float* __restrict__ g, const float* __restrict__ be,
    float* __restrict__ out) {
  int r = blockIdx.x;          // 0..BB*LT-1
  int b = r >> 9, t = r & 511;
  int lane = threadIdx.x;
  const float* rp = res + (size_t)r * DMODEL;
  const float* ap = add ? add + (size_t)b * add_bstride + add_off + (size_t)t * DMODEL
                        : nullptr;
  float v[8];
  float s = 0.f, ss = 0.f;
#pragma unroll
  for (int j = 0; j < 8; ++j) {
    float x = rp[lane + j * 64];
    if (ap) x += ap[lane + j * 64];
    v[j] = x; s += x; ss += x * x;
  }
#pragma unroll
  for (int o = 32; o > 0; o >>= 1) { s += __shfl_xor(s, o); ss += __shfl_xor(ss, o); }
  float m = s * (1.f / 512.f);
  float var = ss * (1.f / 512.f) - m * m;
  float rs = rsqrtf(var + 1e-6f);
#pragma unroll
  for (int j = 0; j < 8; ++j) {
    int c = lane + j * 64;
    out[(size_t)r * DMODEL + c] = (v[j] - m) * rs * g[c] + be[c];
  }
}

// ---------------- orchestration ----------------
extern "C" void kernel_launch(void* const* d_in, const int* in_sizes, int n_in,
                              void* d_out, int out_size, void* d_ws, size_t ws_size,
                              hipStream_t stream) {
  (void)in_sizes; (void)n_in; (void)out_size; (void)ws_size;
  const float* src      = (const float*)d_in[0];
  const int*   tgt      = (const int*)d_in[1];
  const float* emb      = (const float*)d_in[2];
  const float* in_w_s   = (const float*)d_in[3];
  const float* conv_w_s = (const float*)d_in[4];
  const float* conv_b_s = (const float*)d_in[5];
  const float* xproj_s  = (const float*)d_in[6];
  const float* dtw_s    = (const float*)d_in[7];
  const float* dtb_s    = (const float*)d_in[8];
  const float* Alog_s   = (const float*)d_in[9];
  const float* D_s      = (const float*)d_in[10];
  const float* outw_s   = (const float*)d_in[11];
  const float* in_w_c   = (const float*)d_in[12];
  const float* conv_w_c = (const float*)d_in[13];
  const float* conv_b_c = (const float*)d_in[14];
  const float* xproj_c  = (const float*)d_in[15];
  const float* dtw_c    = (const float*)d_in[16];
  const float* dtb_c    = (const float*)d_in[17];
  const float* Alog_c   = (const float*)d_in[18];
  const float* D_c      = (const float*)d_in[19];
  const float* outw_c   = (const float*)d_in[20];
  const float* ffn_w1   = (const float*)d_in[21];
  const float* ffn_b1   = (const float*)d_in[22];
  const float* ffn_w2   = (const float*)d_in[23];
  const float* ffn_b2   = (const float*)d_in[24];
  const float* ln_g     = (const float*)d_in[25];
  const float* ln_b     = (const float*)d_in[26];
  const float* fin_g    = (const float*)d_in[27];
  const float* fin_b    = (const float*)d_in[28];

  // workspace layout (floats)
  float* ws  = (float*)d_ws;
  float* X   = ws;                    // 524288   (2,512,512)
  float* CAT = X + 524288;            // 1048576  (2,1024,512)
  float* XZ  = CAT + 1048576;         // 4194304  (2,1024,2048)  (reused as FFN hidden)
  float* XC  = XZ + 4194304;          // 2097152  (2,1024,1024)
  float* DT  = XC + 2097152;          // 2097152  (2,1024,1024)  (also split-K scratch)
  float* DBL = DT + 2097152;          // 131072   (2,1024,64)
  float* YS  = DBL + 131072;          // 2097152  (2,1024,1024)
  float* T2  = YS + 2097152;          // 1048576  (2,1024,512)

  embed_kernel<<<2048, 256, 0, stream>>>(tgt, emb, X);

  for (int i = 0; i < NLAYERS; ++i) {
    // ---------- self mamba (L = 512) ----------
    gemm128<0><<<dim3(16, 8), 256, 0, stream>>>(
        X, in_w_s + (size_t)i * 1048576, nullptr, XZ, 1024, 2048, 512, 512);
    conv_silu_kernel<<<4096, 256, 0, stream>>>(
        XZ, conv_w_s + (size_t)i * 4096, conv_b_s + (size_t)i * 1024, XC, 512);
    gemm64_split<<<dim3(1, 16, 8), 256, 0, stream>>>(
        XC, xproj_s + (size_t)i * 65536, DT /*scratch*/, 1024, 64, 1024, 1024);
    reduce_sum_kernel<<<256, 256, 0, stream>>>(DT, DBL, 65536, 8);
    gemm64<3><<<dim3(16, 16), 256, 0, stream>>>(
        DBL, dtw_s + (size_t)i * 32768, dtb_s + (size_t)i * 1024, DT, 1024, 1024, 32, 64);
    scan_kernel<<<128, 256, 0, stream>>>(
        DT, DBL, XC, XZ, Alog_s + (size_t)i * 16384, D_s + (size_t)i * 1024, YS, 512);
    gemm64<0><<<dim3(8, 16), 256, 0, stream>>>(
        YS, outw_s + (size_t)i * 524288, nullptr, T2, 1024, 512, 1024, 1024);
    ln_kernel<<<1024, 64, 0, stream>>>(
        X, T2, (long long)512 * 512, 0, ln_g + (size_t)(i * 3 + 0) * 512,
        ln_b + (size_t)(i * 3 + 0) * 512, X);

    // ---------- cross mamba (L = 1024) ----------
    concat_kernel<<<1024, 256, 0, stream>>>(src, X, CAT);
    gemm128<0><<<dim3(16, 16), 256, 0, stream>>>(
        CAT, in_w_c + (size_t)i * 1048576, nullptr, XZ, 2048, 2048, 512, 512);
    conv_silu_kernel<<<8192, 256, 0, stream>>>(
        XZ, conv_w_c + (size_t)i * 4096, conv_b_c + (size_t)i * 1024, XC, 1024);
    gemm64_split<<<dim3(1, 32, 8), 256, 0, stream>>>(
        XC, xproj_c + (size_t)i * 65536, DT /*scratch*/, 2048, 64, 1024, 1024);
    reduce_sum_kernel<<<512, 256, 0, stream>>>(DT, DBL, 131072, 8);
    gemm64<3><<<dim3(16, 32), 256, 0, stream>>>(
        DBL, dtw_c + (size_t)i * 32768, dtb_c + (size_t)i * 1024, DT, 2048, 1024, 32, 64);
    scan_kernel<<<128, 256, 0, stream>>>(
        DT, DBL, XC, XZ, Alog_c + (size_t)i * 16384, D_c + (size_t)i * 1024, YS, 1024);
    gemm64<0><<<dim3(8, 32), 256, 0, stream>>>(
        YS, outw_c + (size_t)i * 524288, nullptr, T2, 2048, 512, 1024, 1024);
    ln_kernel<<<1024, 64, 0, stream>>>(
        X, T2, (long long)1024 * 512, (long long)512 * 512,
        ln_g + (size_t)(i * 3 + 1) * 512, ln_b + (size_t)(i * 3 + 1) * 512, X);

    // ---------- FFN ----------
    gemm128<1><<<dim3(16, 8), 256, 0, stream>>>(
        X, ffn_w1 + (size_t)i * 1048576, ffn_b1 + (size_t)i * 2048, XZ, 1024, 2048, 512, 512);
    gemm64<2><<<dim3(8, 16), 256, 0, stream>>>(
        XZ, ffn_w2 + (size_t)i * 1048576, ffn_b2 + (size_t)i * 512, T2, 1024, 512, 2048, 2048);
    ln_kernel<<<1024, 64, 0, stream>>>(
        X, T2, (long long)512 * 512, 0, ln_g + (size_t)(i * 3 + 2) * 512,
        ln_b + (size_t)(i * 3 + 2) * 512, X);
  }

  // final LN -> d_out
  ln_kernel<<<1024, 64, 0, stream>>>(
      X, nullptr, 0, 0, fin_g, fin_b, (float*)d_out);
}

// Round 2
// 3857.019 us; speedup vs baseline: 1.6628x; 1.6628x over previous
//
#include <hip/hip_runtime.h>
#include <math.h>

#define DMODEL 512
#define DINNER 1024
#define DSTATE 16
#define DTRANK 32
#define NLAYERS 6
#define BB 2
#define LT 512
#define LS 512
#define NCHUNK 16

// ---------------- epilogues ----------------
// 0=none, 1=bias+relu, 2=bias, 3=bias+softplus
template<int EPI>
__device__ __forceinline__ float epi_apply(float acc, float b) {
  if (EPI == 1) { float v = acc + b; return v > 0.f ? v : 0.f; }
  if (EPI == 2) { return acc + b; }
  if (EPI == 3) { float v = acc + b; return fmaxf(v, 0.f) + log1pf(__expf(-fabsf(v))); }
  return acc;
}

// ---------------- embedding + sinusoidal PE ----------------
__global__ __launch_bounds__(256) void embed_kernel(const int* __restrict__ tgt,
    const float* __restrict__ emb, float* __restrict__ X) {
  int i = blockIdx.x * 256 + threadIdx.x;     // over BB*LT*DMODEL
  int d = i & (DMODEL - 1);
  int bt = i >> 9;
  int t = bt & (LT - 1);
  int tok = tgt[bt];
  float div = __expf((float)(d & ~1) * (-9.210340371976184f / (float)DMODEL));
  float ang = (float)t * div;
  float pe = (d & 1) ? cosf(ang) : sinf(ang);
  X[i] = emb[(size_t)tok * DMODEL + d] * 22.627416997969522f + pe;
}

// ---------------- concat [src, x] along time ----------------
__global__ __launch_bounds__(256) void concat_kernel(const float* __restrict__ src,
    const float* __restrict__ X, float* __restrict__ CAT) {
  int i = blockIdx.x * 256 + threadIdx.x;     // float4 index over BB*1024*512/4
  int c = i & 127;
  int r = i >> 7;
  int l = r & 1023;
  int b = r >> 10;
  const float* s = (l < LS) ? (src + ((size_t)b * LS + l) * DMODEL)
                            : (X + ((size_t)b * LT + (l - LS)) * DMODEL);
  ((float4*)CAT)[(size_t)r * 128 + c] = ((const float4*)s)[c];
}

// ---------------- GEMM: C[M,N] = A[M,K] * B[N,K]^T, 128x128 tile ----------------
template<int EPI>
__global__ __launch_bounds__(256) void gemm128(
    const float* __restrict__ A, const float* __restrict__ Bw,
    const float* __restrict__ bias, float* __restrict__ C,
    int M, int N, int K, int lda) {
  __shared__ __align__(16) float As[8][128];
  __shared__ __align__(16) float Bs[8][128];
  const int tid = threadIdx.x;
  const int bn = blockIdx.x * 128;
  const int bm = blockIdx.y * 128;
  const int tx = tid & 15;
  const int ty = tid >> 4;
  const int lrow = tid >> 1;
  const int lk = (tid & 1) * 4;
  float acc[8][8];
#pragma unroll
  for (int i = 0; i < 8; ++i)
#pragma unroll
    for (int j = 0; j < 8; ++j) acc[i][j] = 0.f;

  for (int k0 = 0; k0 < K; k0 += 8) {
    float4 av = *(const float4*)(A + (size_t)(bm + lrow) * lda + k0 + lk);
    float4 bv = *(const float4*)(Bw + (size_t)(bn + lrow) * K + k0 + lk);
    __syncthreads();
    As[lk + 0][lrow] = av.x; As[lk + 1][lrow] = av.y;
    As[lk + 2][lrow] = av.z; As[lk + 3][lrow] = av.w;
    Bs[lk + 0][lrow] = bv.x; Bs[lk + 1][lrow] = bv.y;
    Bs[lk + 2][lrow] = bv.z; Bs[lk + 3][lrow] = bv.w;
    __syncthreads();
#pragma unroll
    for (int kk = 0; kk < 8; ++kk) {
      float4 a0 = *(const float4*)&As[kk][ty * 8];
      float4 a1 = *(const float4*)&As[kk][ty * 8 + 4];
      float4 b0 = *(const float4*)&Bs[kk][tx * 8];
      float4 b1 = *(const float4*)&Bs[kk][tx * 8 + 4];
      float ar[8] = {a0.x, a0.y, a0.z, a0.w, a1.x, a1.y, a1.z, a1.w};
      float br[8] = {b0.x, b0.y, b0.z, b0.w, b1.x, b1.y, b1.z, b1.w};
#pragma unroll
      for (int i = 0; i < 8; ++i)
#pragma unroll
        for (int j = 0; j < 8; ++j)
          acc[i][j] = fmaf(ar[i], br[j], acc[i][j]);
    }
  }
  float bv8[8];
  if (EPI != 0) {
#pragma unroll
    for (int j = 0; j < 8; ++j) bv8[j] = bias[bn + tx * 8 + j];
  } else {
#pragma unroll
    for (int j = 0; j < 8; ++j) bv8[j] = 0.f;
  }
#pragma unroll
  for (int i = 0; i < 8; ++i) {
    size_t crow = (size_t)(bm + ty * 8 + i) * N + bn + tx * 8;
#pragma unroll
    for (int j = 0; j < 8; ++j)
      C[crow + j] = epi_apply<EPI>(acc[i][j], bv8[j]);
  }
}

// ---------------- GEMM: 64x64 tile, 4x4 microtile ----------------
template<int EPI>
__global__ __launch_bounds__(256) void gemm64(
    const float* __restrict__ A, const float* __restrict__ Bw,
    const float* __restrict__ bias, float* __restrict__ C,
    int M, int N, int K, int lda) {
  __shared__ __align__(16) float As[16][64];
  __shared__ __align__(16) float Bs[16][64];
  const int tid = threadIdx.x;
  const int bn = blockIdx.x * 64;
  const int bm = blockIdx.y * 64;
  const int tx = tid & 15;
  const int ty = tid >> 4;
  const int lrow = tid >> 2;
  const int lk = (tid & 3) * 4;
  float acc[4][4];
#pragma unroll
  for (int i = 0; i < 4; ++i)
#pragma unroll
    for (int j = 0; j < 4; ++j) acc[i][j] = 0.f;

  for (int k0 = 0; k0 < K; k0 += 16) {
    float4 av = *(const float4*)(A + (size_t)(bm + lrow) * lda + k0 + lk);
    float4 bv = *(const float4*)(Bw + (size_t)(bn + lrow) * K + k0 + lk);
    __syncthreads();
    As[lk + 0][lrow] = av.x; As[lk + 1][lrow] = av.y;
    As[lk + 2][lrow] = av.z; As[lk + 3][lrow] = av.w;
    Bs[lk + 0][lrow] = bv.x; Bs[lk + 1][lrow] = bv.y;
    Bs[lk + 2][lrow] = bv.z; Bs[lk + 3][lrow] = bv.w;
    __syncthreads();
#pragma unroll
    for (int kk = 0; kk < 16; ++kk) {
      float4 a = *(const float4*)&As[kk][ty * 4];
      float4 b = *(const float4*)&Bs[kk][tx * 4];
      float ar[4] = {a.x, a.y, a.z, a.w};
      float br[4] = {b.x, b.y, b.z, b.w};
#pragma unroll
      for (int i = 0; i < 4; ++i)
#pragma unroll
        for (int j = 0; j < 4; ++j)
          acc[i][j] = fmaf(ar[i], br[j], acc[i][j]);
    }
  }
  float bv4[4];
  if (EPI != 0) {
#pragma unroll
    for (int j = 0; j < 4; ++j) bv4[j] = bias[bn + tx * 4 + j];
  } else {
#pragma unroll
    for (int j = 0; j < 4; ++j) bv4[j] = 0.f;
  }
#pragma unroll
  for (int i = 0; i < 4; ++i) {
    size_t crow = (size_t)(bm + ty * 4 + i) * N + bn + tx * 4;
#pragma unroll
    for (int j = 0; j < 4; ++j)
      C[crow + j] = epi_apply<EPI>(acc[i][j], bv4[j]);
  }
}

// ---------------- GEMM 64x64 with split-K (partials, no epilogue) ----------------
__global__ __launch_bounds__(256) void gemm64_split(
    const float* __restrict__ A, const float* __restrict__ Bw,
    float* __restrict__ P, int M, int N, int K, int lda) {
  __shared__ __align__(16) float As[16][64];
  __shared__ __align__(16) float Bs[16][64];
  const int tid = threadIdx.x;
  const int bn = blockIdx.x * 64;
  const int bm = blockIdx.y * 64;
  const int nz = gridDim.z;
  const int kc = K / nz;
  const int kbeg = blockIdx.z * kc;
  const int tx = tid & 15;
  const int ty = tid >> 4;
  const int lrow = tid >> 2;
  const int lk = (tid & 3) * 4;
  float acc[4][4];
#pragma unroll
  for (int i = 0; i < 4; ++i)
#pragma unroll
    for (int j = 0; j < 4; ++j) acc[i][j] = 0.f;

  for (int k0 = kbeg; k0 < kbeg + kc; k0 += 16) {
    float4 av = *(const float4*)(A + (size_t)(bm + lrow) * lda + k0 + lk);
    float4 bv = *(const float4*)(Bw + (size_t)(bn + lrow) * K + k0 + lk);
    __syncthreads();
    As[lk + 0][lrow] = av.x; As[lk + 1][lrow] = av.y;
    As[lk + 2][lrow] = av.z; As[lk + 3][lrow] = av.w;
    Bs[lk + 0][lrow] = bv.x; Bs[lk + 1][lrow] = bv.y;
    Bs[lk + 2][lrow] = bv.z; Bs[lk + 3][lrow] = bv.w;
    __syncthreads();
#pragma unroll
    for (int kk = 0; kk < 16; ++kk) {
      float4 a = *(const float4*)&As[kk][ty * 4];
      float4 b = *(const float4*)&Bs[kk][tx * 4];
      float ar[4] = {a.x, a.y, a.z, a.w};
      float br[4] = {b.x, b.y, b.z, b.w};
#pragma unroll
      for (int i = 0; i < 4; ++i)
#pragma unroll
        for (int j = 0; j < 4; ++j)
          acc[i][j] = fmaf(ar[i], br[j], acc[i][j]);
    }
  }
  float* Pz = P + (size_t)blockIdx.z * M * N;
#pragma unroll
  for (int i = 0; i < 4; ++i) {
    size_t crow = (size_t)(bm + ty * 4 + i) * N + bn + tx * 4;
#pragma unroll
    for (int j = 0; j < 4; ++j)
      Pz[crow + j] = acc[i][j];
  }
}

__global__ __launch_bounds__(256) void reduce_sum_kernel(const float* __restrict__ P,
    float* __restrict__ C, int total, int nz) {
  int i = blockIdx.x * 256 + threadIdx.x;
  if (i >= total) return;
  float s = 0.f;
  for (int z = 0; z < nz; ++z) s += P[(size_t)z * total + i];
  C[i] = s;
}

// ---------------- causal depthwise conv (k=4) + bias + silu ----------------
__global__ __launch_bounds__(256) void conv_silu_kernel(
    const float* __restrict__ xz, const float* __restrict__ w,
    const float* __restrict__ bias, float* __restrict__ out, int L) {
  int idx = blockIdx.x * 256 + threadIdx.x;   // over BB*L*DINNER
  int d = idx & (DINNER - 1);
  int bt = idx >> 10;
  int b = bt / L;
  int t = bt - b * L;
  const float* col = xz + ((size_t)b * L) * (2 * DINNER) + d;
  float acc = bias[d];
#pragma unroll
  for (int k = 0; k < 4; ++k) {
    int tt = t - 3 + k;
    if (tt >= 0) acc = fmaf(col[(size_t)tt * (2 * DINNER)], w[d * 4 + k], acc);
  }
  float sig = 1.f / (1.f + __expf(-acc));
  out[idx] = acc * sig;
}

// ---------------- chunked selective scan ----------------
// state id s = ((b*1024 + d)*16 + n), 32768 states total.
// pass1: per chunk, scan from h=0; emit P = prod(dA), S = local final h.
__global__ __launch_bounds__(256) void scan_pass1(
    const float* __restrict__ dt, const float* __restrict__ dbl,
    const float* __restrict__ u, const float* __restrict__ Alog,
    float* __restrict__ P, float* __restrict__ S, int L, int CL) {
  int s = blockIdx.x * 256 + threadIdx.x;     // 0..32767
  int n = s & 15;
  int d = (s >> 4) & 1023;
  int b = s >> 14;
  int c = blockIdx.y;
  int t0 = c * CL;
  float A = -__expf(Alog[d * DSTATE + n]);
  const float* dtp = dt + ((size_t)b * L + t0) * DINNER + d;
  const float* up  = u  + ((size_t)b * L + t0) * DINNER + d;
  const float* Bp  = dbl + ((size_t)b * L + t0) * 64 + DTRANK + n;
  float h = 0.f, Pp = 1.f;
  for (int t = 0; t < CL; ++t) {
    float dtv = dtp[(size_t)t * DINNER];
    float uv  = up[(size_t)t * DINNER];
    float Bv  = Bp[(size_t)t * 64];
    float dA = __expf(dtv * A);
    Pp *= dA;
    h = fmaf(dA, h, dtv * uv * Bv);
  }
  P[(size_t)c * 32768 + s] = Pp;
  S[(size_t)c * 32768 + s] = h;
}

// pass mid: serial scan over chunks -> h_in per chunk
__global__ __launch_bounds__(256) void scan_mid(
    const float* __restrict__ P, const float* __restrict__ S,
    float* __restrict__ HIN, int C) {
  int s = blockIdx.x * 256 + threadIdx.x;
  float h = 0.f;
  for (int c = 0; c < C; ++c) {
    HIN[(size_t)c * 32768 + s] = h;
    h = fmaf(P[(size_t)c * 32768 + s], h, S[(size_t)c * 32768 + s]);
  }
}

// pass2: re-scan chunk from h_in, reduce over n, emit gated y
__global__ __launch_bounds__(256) void scan_pass2(
    const float* __restrict__ dt, const float* __restrict__ dbl,
    const float* __restrict__ u, const float* __restrict__ xz,
    const float* __restrict__ Alog, const float* __restrict__ Dsk,
    const float* __restrict__ HIN, float* __restrict__ ys, int L, int CL) {
  int tid = threadIdx.x;
  int g = tid >> 4, n = tid & 15;
  int chan = blockIdx.x * 16 + g;    // 0..2047 = b*1024+d
  int b = chan >> 10, d = chan & 1023;
  int c = blockIdx.y;
  int t0 = c * CL;
  int s = (chan << 4) | n;
  float A = -__expf(Alog[d * DSTATE + n]);
  float Dv = Dsk[d];
  const float* dtp = dt + ((size_t)b * L + t0) * DINNER + d;
  const float* up  = u  + ((size_t)b * L + t0) * DINNER + d;
  const float* zp  = xz + ((size_t)b * L + t0) * (2 * DINNER) + DINNER + d;
  const float* Bp  = dbl + ((size_t)b * L + t0) * 64 + DTRANK + n;
  const float* Cp  = Bp + DSTATE;
  float* yp = ys + ((size_t)b * L + t0) * DINNER + d;
  float h = HIN[(size_t)c * 32768 + s];
  for (int t = 0; t < CL; ++t) {
    float dtv = dtp[(size_t)t * DINNER];
    float uv  = up[(size_t)t * DINNER];
    float Bv  = Bp[(size_t)t * 64];
    float Cv  = Cp[(size_t)t * 64];
    float dA = __expf(dtv * A);
    h = fmaf(dA, h, dtv * uv * Bv);
    float r = h * Cv;
    r += __shfl_xor(r, 1);
    r += __shfl_xor(r, 2);
    r += __shfl_xor(r, 4);
    r += __shfl_xor(r, 8);
    if (n == 0) {
      float zv = zp[(size_t)t * (2 * DINNER)];
      float sig = 1.f / (1.f + __expf(-zv));
      yp[(size_t)t * DINNER] = (r + uv * Dv) * (zv * sig);
    }
  }
}

// ---------------- LayerNorm (optional residual add), row = 512 ----------------
__global__ __launch_bounds__(64) void ln_kernel(
    const float* __restrict__ res, const float* __restrict__ add,
    long long add_bstride, long long add_off,
    const float* __restrict__ g, const float* __restrict__ be,
    float* __restrict__ out) {
  int r = blockIdx.x;          // 0..BB*LT-1
  int b = r >> 9, t = r & 511;
  int lane = threadIdx.x;
  const float* rp = res + (size_t)r * DMODEL;
  const float* ap = add ? add + (size_t)b * add_bstride + add_off + (size_t)t * DMODEL
                        : nullptr;
  float v[8];
  float s = 0.f, ss = 0.f;
#pragma unroll
  for (int j = 0; j < 8; ++j) {
    float x = rp[lane + j * 64];
    if (ap) x += ap[lane + j * 64];
    v[j] = x; s += x; ss += x * x;
  }
#pragma unroll
  for (int o = 32; o > 0; o >>= 1) { s += __shfl_xor(s, o); ss += __shfl_xor(ss, o); }
  float m = s * (1.f / 512.f);
  float var = ss * (1.f / 512.f) - m * m;
  float rs = rsqrtf(var + 1e-6f);
#pragma unroll
  for (int j = 0; j < 8; ++j) {
    int c = lane + j * 64;
    out[(size_t)r * DMODEL + c] = (v[j] - m) * rs * g[c] + be[c];
  }
}

// ---------------- orchestration ----------------
extern "C" void kernel_launch(void* const* d_in, const int* in_sizes, int n_in,
                              void* d_out, int out_size, void* d_ws, size_t ws_size,
                              hipStream_t stream) {
  (void)in_sizes; (void)n_in; (void)out_size; (void)ws_size;
  const float* src      = (const float*)d_in[0];
  const int*   tgt      = (const int*)d_in[1];
  const float* emb      = (const float*)d_in[2];
  const float* in_w_s   = (const float*)d_in[3];
  const float* conv_w_s = (const float*)d_in[4];
  const float* conv_b_s = (const float*)d_in[5];
  const float* xproj_s  = (const float*)d_in[6];
  const float* dtw_s    = (const float*)d_in[7];
  const float* dtb_s    = (const float*)d_in[8];
  const float* Alog_s   = (const float*)d_in[9];
  const float* D_s      = (const float*)d_in[10];
  const float* outw_s   = (const float*)d_in[11];
  const float* in_w_c   = (const float*)d_in[12];
  const float* conv_w_c = (const float*)d_in[13];
  const float* conv_b_c = (const float*)d_in[14];
  const float* xproj_c  = (const float*)d_in[15];
  const float* dtw_c    = (const float*)d_in[16];
  const float* dtb_c    = (const float*)d_in[17];
  const float* Alog_c   = (const float*)d_in[18];
  const float* D_c      = (const float*)d_in[19];
  const float* outw_c   = (const float*)d_in[20];
  const float* ffn_w1   = (const float*)d_in[21];
  const float* ffn_b1   = (const float*)d_in[22];
  const float* ffn_w2   = (const float*)d_in[23];
  const float* ffn_b2   = (const float*)d_in[24];
  const float* ln_g     = (const float*)d_in[25];
  const float* ln_b     = (const float*)d_in[26];
  const float* fin_g    = (const float*)d_in[27];
  const float* fin_b    = (const float*)d_in[28];

  // workspace layout (floats)
  float* ws  = (float*)d_ws;
  float* X   = ws;                    // 524288   (2,512,512)
  float* CAT = X + 524288;            // 1048576  (2,1024,512)  (also scan HIN scratch)
  float* XZ  = CAT + 1048576;         // 4194304  (2,1024,2048) (reused as FFN hidden)
  float* XC  = XZ + 4194304;          // 2097152  (2,1024,1024)
  float* DT  = XC + 2097152;          // 2097152  (2,1024,1024) (also split-K scratch)
  float* DBL = DT + 2097152;          // 131072   (2,1024,64)
  float* YS  = DBL + 131072;          // 2097152  (2,1024,1024)
  float* T2  = YS + 2097152;          // 1048576  (2,1024,512)  (also scan P/S scratch)

  float* SC_P   = T2;                 // 524288 = NCHUNK*32768
  float* SC_S   = T2 + 524288;        // 524288
  float* SC_HIN = CAT;                // 524288 (CAT is dead at scan time)

  embed_kernel<<<2048, 256, 0, stream>>>(tgt, emb, X);

  for (int i = 0; i < NLAYERS; ++i) {
    // ---------- self mamba (L = 512, CL = 32) ----------
    gemm128<0><<<dim3(16, 8), 256, 0, stream>>>(
        X, in_w_s + (size_t)i * 1048576, nullptr, XZ, 1024, 2048, 512, 512);
    conv_silu_kernel<<<4096, 256, 0, stream>>>(
        XZ, conv_w_s + (size_t)i * 4096, conv_b_s + (size_t)i * 1024, XC, 512);
    gemm64_split<<<dim3(1, 16, 8), 256, 0, stream>>>(
        XC, xproj_s + (size_t)i * 65536, DT /*scratch*/, 1024, 64, 1024, 1024);
    reduce_sum_kernel<<<256, 256, 0, stream>>>(DT, DBL, 65536, 8);
    gemm64<3><<<dim3(16, 16), 256, 0, stream>>>(
        DBL, dtw_s + (size_t)i * 32768, dtb_s + (size_t)i * 1024, DT, 1024, 1024, 32, 64);
    scan_pass1<<<dim3(128, NCHUNK), 256, 0, stream>>>(
        DT, DBL, XC, Alog_s + (size_t)i * 16384, SC_P, SC_S, 512, 512 / NCHUNK);
    scan_mid<<<128, 256, 0, stream>>>(SC_P, SC_S, SC_HIN, NCHUNK);
    scan_pass2<<<dim3(128, NCHUNK), 256, 0, stream>>>(
        DT, DBL, XC, XZ, Alog_s + (size_t)i * 16384, D_s + (size_t)i * 1024,
        SC_HIN, YS, 512, 512 / NCHUNK);
    gemm64<0><<<dim3(8, 16), 256, 0, stream>>>(
        YS, outw_s + (size_t)i * 524288, nullptr, T2, 1024, 512, 1024, 1024);
    ln_kernel<<<1024, 64, 0, stream>>>(
        X, T2, (long long)512 * 512, 0, ln_g + (size_t)(i * 3 + 0) * 512,
        ln_b + (size_t)(i * 3 + 0) * 512, X);

    // ---------- cross mamba (L = 1024, CL = 64) ----------
    concat_kernel<<<1024, 256, 0, stream>>>(src, X, CAT);
    gemm128<0><<<dim3(16, 16), 256, 0, stream>>>(
        CAT, in_w_c + (size_t)i * 1048576, nullptr, XZ, 2048, 2048, 512, 512);
    conv_silu_kernel<<<8192, 256, 0, stream>>>(
        XZ, conv_w_c + (size_t)i * 4096, conv_b_c + (size_t)i * 1024, XC, 1024);
    gemm64_split<<<dim3(1, 32, 8), 256, 0, stream>>>(
        XC, xproj_c + (size_t)i * 65536, DT /*scratch*/, 2048, 64, 1024, 1024);
    reduce_sum_kernel<<<512, 256, 0, stream>>>(DT, DBL, 131072, 8);
    gemm64<3><<<dim3(16, 32), 256, 0, stream>>>(
        DBL, dtw_c + (size_t)i * 32768, dtb_c + (size_t)i * 1024, DT, 2048, 1024, 32, 64);
    scan_pass1<<<dim3(128, NCHUNK), 256, 0, stream>>>(
        DT, DBL, XC, Alog_c + (size_t)i * 16384, SC_P, SC_S, 1024, 1024 / NCHUNK);
    scan_mid<<<128, 256, 0, stream>>>(SC_P, SC_S, SC_HIN, NCHUNK);
    scan_pass2<<<dim3(128, NCHUNK), 256, 0, stream>>>(
        DT, DBL, XC, XZ, Alog_c + (size_t)i * 16384, D_c + (size_t)i * 1024,
        SC_HIN, YS, 1024, 1024 / NCHUNK);
    gemm64<0><<<dim3(8, 32), 256, 0, stream>>>(
        YS, outw_c + (size_t)i * 524288, nullptr, T2, 2048, 512, 1024, 1024);
    ln_kernel<<<1024, 64, 0, stream>>>(
        X, T2, (long long)1024 * 512, (long long)512 * 512,
        ln_g + (size_t)(i * 3 + 1) * 512, ln_b + (size_t)(i * 3 + 1) * 512, X);

    // ---------- FFN ----------
    gemm128<1><<<dim3(16, 8), 256, 0, stream>>>(
        X, ffn_w1 + (size_t)i * 1048576, ffn_b1 + (size_t)i * 2048, XZ, 1024, 2048, 512, 512);
    gemm64<2><<<dim3(8, 16), 256, 0, stream>>>(
        XZ, ffn_w2 + (size_t)i * 1048576, ffn_b2 + (size_t)i * 512, T2, 1024, 512, 2048, 2048);
    ln_kernel<<<1024, 64, 0, stream>>>(
        X, T2, (long long)512 * 512, 0, ln_g + (size_t)(i * 3 + 2) * 512,
        ln_b + (size_t)(i * 3 + 2) * 512, X);
  }

  // final LN -> d_out
  ln_kernel<<<1024, 64, 0, stream>>>(
      X, nullptr, 0, 0, fin_g, fin_b, (float*)d_out);
}

// Round 3
// 2415.649 us; speedup vs baseline: 2.6549x; 1.5967x over previous
//
#include <hip/hip_runtime.h>
#include <math.h>

#define DMODEL 512
#define DINNER 1024
#define DSTATE 16
#define DTRANK 32
#define NLAYERS 6
#define BB 2
#define LT 512
#define LS 512
#define NCHUNK 16

typedef __attribute__((ext_vector_type(8))) short bf16x8;
typedef __attribute__((ext_vector_type(4))) float f32x4;

// fp32 -> bf16 round-to-nearest-even
__device__ __forceinline__ unsigned short f2bf(float f) {
  unsigned u = __float_as_uint(f);
  u += 0x7fffu + ((u >> 16) & 1u);
  return (unsigned short)(u >> 16);
}

// ---------------- epilogues ----------------
// 0=none, 1=bias+relu, 2=bias, 3=bias+softplus
template<int EPI>
__device__ __forceinline__ float epi_apply(float acc, float b) {
  if (EPI == 1) { float v = acc + b; return v > 0.f ? v : 0.f; }
  if (EPI == 2) { return acc + b; }
  if (EPI == 3) { float v = acc + b; return fmaxf(v, 0.f) + log1pf(__expf(-fabsf(v))); }
  return acc;
}

// ---------------- embedding + sinusoidal PE ----------------
__global__ __launch_bounds__(256) void embed_kernel(const int* __restrict__ tgt,
    const float* __restrict__ emb, float* __restrict__ X) {
  int i = blockIdx.x * 256 + threadIdx.x;
  int d = i & (DMODEL - 1);
  int bt = i >> 9;
  int t = bt & (LT - 1);
  int tok = tgt[bt];
  float div = __expf((float)(d & ~1) * (-9.210340371976184f / (float)DMODEL));
  float ang = (float)t * div;
  float pe = (d & 1) ? cosf(ang) : sinf(ang);
  X[i] = emb[(size_t)tok * DMODEL + d] * 22.627416997969522f + pe;
}

// ---------------- concat [src, x] along time ----------------
__global__ __launch_bounds__(256) void concat_kernel(const float* __restrict__ src,
    const float* __restrict__ X, float* __restrict__ CAT) {
  int i = blockIdx.x * 256 + threadIdx.x;
  int c = i & 127;
  int r = i >> 7;
  int l = r & 1023;
  int b = r >> 10;
  const float* s = (l < LS) ? (src + ((size_t)b * LS + l) * DMODEL)
                            : (X + ((size_t)b * LT + (l - LS)) * DMODEL);
  ((float4*)CAT)[(size_t)r * 128 + c] = ((const float4*)s)[c];
}

// ---------------- MFMA GEMM: C[M,N] = A[M,K] * Bw[N,K]^T ----------------
// 128x128 tile, BK=32, 4 waves (2x2), 64x64 per wave (4x4 frags of 16x16)
template<int EPI>
__global__ __launch_bounds__(256) void mgemm128(
    const float* __restrict__ A, const float* __restrict__ Bw,
    const float* __restrict__ bias, float* __restrict__ C,
    int M, int N, int K, int lda) {
  __shared__ unsigned short As[128 * 40];
  __shared__ unsigned short Bs[128 * 40];
  const int tid = threadIdx.x;
  const int bn = blockIdx.x * 128;
  const int bm = blockIdx.y * 128;
  const int lane = tid & 63;
  const int w = tid >> 6;
  const int wr = (w >> 1) * 64;
  const int wc = (w & 1) * 64;
  const int l15 = lane & 15;
  const int l4 = lane >> 4;       // 0..3
  const int koff = l4 * 8;
  f32x4 acc[4][4] = {};

  for (int k0 = 0; k0 < K; k0 += 32) {
    float4 av[4], bv[4];
#pragma unroll
    for (int i = 0; i < 4; ++i) {
      int f = tid + 256 * i;
      int row = f >> 3, k4 = f & 7;
      av[i] = *(const float4*)(A + (size_t)(bm + row) * lda + k0 + k4 * 4);
      bv[i] = *(const float4*)(Bw + (size_t)(bn + row) * K + k0 + k4 * 4);
    }
    __syncthreads();
#pragma unroll
    for (int i = 0; i < 4; ++i) {
      int f = tid + 256 * i;
      int row = f >> 3, k4 = f & 7;
      *(ushort4*)&As[row * 40 + k4 * 4] =
          make_ushort4(f2bf(av[i].x), f2bf(av[i].y), f2bf(av[i].z), f2bf(av[i].w));
      *(ushort4*)&Bs[row * 40 + k4 * 4] =
          make_ushort4(f2bf(bv[i].x), f2bf(bv[i].y), f2bf(bv[i].z), f2bf(bv[i].w));
    }
    __syncthreads();
    bf16x8 afr[4], bfr[4];
#pragma unroll
    for (int i = 0; i < 4; ++i) {
      afr[i] = *(const bf16x8*)&As[(wr + i * 16 + l15) * 40 + koff];
      bfr[i] = *(const bf16x8*)&Bs[(wc + i * 16 + l15) * 40 + koff];
    }
#pragma unroll
    for (int fr = 0; fr < 4; ++fr)
#pragma unroll
      for (int fc = 0; fc < 4; ++fc)
        acc[fr][fc] = __builtin_amdgcn_mfma_f32_16x16x32_bf16(
            afr[fr], bfr[fc], acc[fr][fc], 0, 0, 0);
  }

#pragma unroll
  for (int fc = 0; fc < 4; ++fc) {
    int col = bn + wc + fc * 16 + l15;
    float bvs = (EPI != 0) ? bias[col] : 0.f;
#pragma unroll
    for (int fr = 0; fr < 4; ++fr) {
      int row0 = bm + wr + fr * 16 + l4 * 4;
#pragma unroll
      for (int r = 0; r < 4; ++r)
        C[(size_t)(row0 + r) * N + col] = epi_apply<EPI>(acc[fr][fc][r], bvs);
    }
  }
}

// 64x64 tile, BK=32, 4 waves (2x2), 32x32 per wave (2x2 frags)
template<int EPI>
__global__ __launch_bounds__(256) void mgemm64(
    const float* __restrict__ A, const float* __restrict__ Bw,
    const float* __restrict__ bias, float* __restrict__ C,
    int M, int N, int K, int lda) {
  __shared__ unsigned short As[64 * 40];
  __shared__ unsigned short Bs[64 * 40];
  const int tid = threadIdx.x;
  const int bn = blockIdx.x * 64;
  const int bm = blockIdx.y * 64;
  const int lane = tid & 63;
  const int w = tid >> 6;
  const int wr = (w >> 1) * 32;
  const int wc = (w & 1) * 32;
  const int l15 = lane & 15;
  const int l4 = lane >> 4;
  const int koff = l4 * 8;
  f32x4 acc[2][2] = {};

  for (int k0 = 0; k0 < K; k0 += 32) {
    float4 av[2], bv[2];
#pragma unroll
    for (int i = 0; i < 2; ++i) {
      int f = tid + 256 * i;
      int row = f >> 3, k4 = f & 7;
      av[i] = *(const float4*)(A + (size_t)(bm + row) * lda + k0 + k4 * 4);
      bv[i] = *(const float4*)(Bw + (size_t)(bn + row) * K + k0 + k4 * 4);
    }
    __syncthreads();
#pragma unroll
    for (int i = 0; i < 2; ++i) {
      int f = tid + 256 * i;
      int row = f >> 3, k4 = f & 7;
      *(ushort4*)&As[row * 40 + k4 * 4] =
          make_ushort4(f2bf(av[i].x), f2bf(av[i].y), f2bf(av[i].z), f2bf(av[i].w));
      *(ushort4*)&Bs[row * 40 + k4 * 4] =
          make_ushort4(f2bf(bv[i].x), f2bf(bv[i].y), f2bf(bv[i].z), f2bf(bv[i].w));
    }
    __syncthreads();
    bf16x8 afr[2], bfr[2];
#pragma unroll
    for (int i = 0; i < 2; ++i) {
      afr[i] = *(const bf16x8*)&As[(wr + i * 16 + l15) * 40 + koff];
      bfr[i] = *(const bf16x8*)&Bs[(wc + i * 16 + l15) * 40 + koff];
    }
#pragma unroll
    for (int fr = 0; fr < 2; ++fr)
#pragma unroll
      for (int fc = 0; fc < 2; ++fc)
        acc[fr][fc] = __builtin_amdgcn_mfma_f32_16x16x32_bf16(
            afr[fr], bfr[fc], acc[fr][fc], 0, 0, 0);
  }

#pragma unroll
  for (int fc = 0; fc < 2; ++fc) {
    int col = bn + wc + fc * 16 + l15;
    float bvs = (EPI != 0) ? bias[col] : 0.f;
#pragma unroll
    for (int fr = 0; fr < 2; ++fr) {
      int row0 = bm + wr + fr * 16 + l4 * 4;
#pragma unroll
      for (int r = 0; r < 4; ++r)
        C[(size_t)(row0 + r) * N + col] = epi_apply<EPI>(acc[fr][fc][r], bvs);
    }
  }
}

// ---------------- fp32 GEMM 64x64 with split-K (xproj only, N=64) ----------------
__global__ __launch_bounds__(256) void gemm64_split(
    const float* __restrict__ A, const float* __restrict__ Bw,
    float* __restrict__ P, int M, int N, int K, int lda) {
  __shared__ __align__(16) float As[16][64];
  __shared__ __align__(16) float Bs[16][64];
  const int tid = threadIdx.x;
  const int bn = blockIdx.x * 64;
  const int bm = blockIdx.y * 64;
  const int nz = gridDim.z;
  const int kc = K / nz;
  const int kbeg = blockIdx.z * kc;
  const int tx = tid & 15;
  const int ty = tid >> 4;
  const int lrow = tid >> 2;
  const int lk = (tid & 3) * 4;
  float acc[4][4];
#pragma unroll
  for (int i = 0; i < 4; ++i)
#pragma unroll
    for (int j = 0; j < 4; ++j) acc[i][j] = 0.f;

  for (int k0 = kbeg; k0 < kbeg + kc; k0 += 16) {
    float4 av = *(const float4*)(A + (size_t)(bm + lrow) * lda + k0 + lk);
    float4 bv = *(const float4*)(Bw + (size_t)(bn + lrow) * K + k0 + lk);
    __syncthreads();
    As[lk + 0][lrow] = av.x; As[lk + 1][lrow] = av.y;
    As[lk + 2][lrow] = av.z; As[lk + 3][lrow] = av.w;
    Bs[lk + 0][lrow] = bv.x; Bs[lk + 1][lrow] = bv.y;
    Bs[lk + 2][lrow] = bv.z; Bs[lk + 3][lrow] = bv.w;
    __syncthreads();
#pragma unroll
    for (int kk = 0; kk < 16; ++kk) {
      float4 a = *(const float4*)&As[kk][ty * 4];
      float4 b = *(const float4*)&Bs[kk][tx * 4];
      float ar[4] = {a.x, a.y, a.z, a.w};
      float br[4] = {b.x, b.y, b.z, b.w};
#pragma unroll
      for (int i = 0; i < 4; ++i)
#pragma unroll
        for (int j = 0; j < 4; ++j)
          acc[i][j] = fmaf(ar[i], br[j], acc[i][j]);
    }
  }
  float* Pz = P + (size_t)blockIdx.z * M * N;
#pragma unroll
  for (int i = 0; i < 4; ++i) {
    size_t crow = (size_t)(bm + ty * 4 + i) * N + bn + tx * 4;
#pragma unroll
    for (int j = 0; j < 4; ++j)
      Pz[crow + j] = acc[i][j];
  }
}

__global__ __launch_bounds__(256) void reduce_sum_kernel(const float* __restrict__ P,
    float* __restrict__ C, int total, int nz) {
  int i = blockIdx.x * 256 + threadIdx.x;
  if (i >= total) return;
  float s = 0.f;
  for (int z = 0; z < nz; ++z) s += P[(size_t)z * total + i];
  C[i] = s;
}

// ---------------- causal depthwise conv (k=4) + bias + silu ----------------
__global__ __launch_bounds__(256) void conv_silu_kernel(
    const float* __restrict__ xz, const float* __restrict__ w,
    const float* __restrict__ bias, float* __restrict__ out, int L) {
  int idx = blockIdx.x * 256 + threadIdx.x;
  int d = idx & (DINNER - 1);
  int bt = idx >> 10;
  int b = bt / L;
  int t = bt - b * L;
  const float* col = xz + ((size_t)b * L) * (2 * DINNER) + d;
  float acc = bias[d];
#pragma unroll
  for (int k = 0; k < 4; ++k) {
    int tt = t - 3 + k;
    if (tt >= 0) acc = fmaf(col[(size_t)tt * (2 * DINNER)], w[d * 4 + k], acc);
  }
  float sig = 1.f / (1.f + __expf(-acc));
  out[idx] = acc * sig;
}

// ---------------- chunked selective scan ----------------
__global__ __launch_bounds__(256) void scan_pass1(
    const float* __restrict__ dt, const float* __restrict__ dbl,
    const float* __restrict__ u, const float* __restrict__ Alog,
    float* __restrict__ P, float* __restrict__ S, int L, int CL) {
  int s = blockIdx.x * 256 + threadIdx.x;
  int n = s & 15;
  int d = (s >> 4) & 1023;
  int b = s >> 14;
  int c = blockIdx.y;
  int t0 = c * CL;
  float A = -__expf(Alog[d * DSTATE + n]);
  const float* dtp = dt + ((size_t)b * L + t0) * DINNER + d;
  const float* up  = u  + ((size_t)b * L + t0) * DINNER + d;
  const float* Bp  = dbl + ((size_t)b * L + t0) * 64 + DTRANK + n;
  float h = 0.f, Pp = 1.f;
  for (int t = 0; t < CL; ++t) {
    float dtv = dtp[(size_t)t * DINNER];
    float uv  = up[(size_t)t * DINNER];
    float Bv  = Bp[(size_t)t * 64];
    float dA = __expf(dtv * A);
    Pp *= dA;
    h = fmaf(dA, h, dtv * uv * Bv);
  }
  P[(size_t)c * 32768 + s] = Pp;
  S[(size_t)c * 32768 + s] = h;
}

__global__ __launch_bounds__(256) void scan_mid(
    const float* __restrict__ P, const float* __restrict__ S,
    float* __restrict__ HIN, int C) {
  int s = blockIdx.x * 256 + threadIdx.x;
  float h = 0.f;
  for (int c = 0; c < C; ++c) {
    HIN[(size_t)c * 32768 + s] = h;
    h = fmaf(P[(size_t)c * 32768 + s], h, S[(size_t)c * 32768 + s]);
  }
}

__global__ __launch_bounds__(256) void scan_pass2(
    const float* __restrict__ dt, const float* __restrict__ dbl,
    const float* __restrict__ u, const float* __restrict__ xz,
    const float* __restrict__ Alog, const float* __restrict__ Dsk,
    const float* __restrict__ HIN, float* __restrict__ ys, int L, int CL) {
  int tid = threadIdx.x;
  int g = tid >> 4, n = tid & 15;
  int chan = blockIdx.x * 16 + g;
  int b = chan >> 10, d = chan & 1023;
  int c = blockIdx.y;
  int t0 = c * CL;
  int s = (chan << 4) | n;
  float A = -__expf(Alog[d * DSTATE + n]);
  float Dv = Dsk[d];
  const float* dtp = dt + ((size_t)b * L + t0) * DINNER + d;
  const float* up  = u  + ((size_t)b * L + t0) * DINNER + d;
  const float* zp  = xz + ((size_t)b * L + t0) * (2 * DINNER) + DINNER + d;
  const float* Bp  = dbl + ((size_t)b * L + t0) * 64 + DTRANK + n;
  const float* Cp  = Bp + DSTATE;
  float* yp = ys + ((size_t)b * L + t0) * DINNER + d;
  float h = HIN[(size_t)c * 32768 + s];
  for (int t = 0; t < CL; ++t) {
    float dtv = dtp[(size_t)t * DINNER];
    float uv  = up[(size_t)t * DINNER];
    float Bv  = Bp[(size_t)t * 64];
    float Cv  = Cp[(size_t)t * 64];
    float dA = __expf(dtv * A);
    h = fmaf(dA, h, dtv * uv * Bv);
    float r = h * Cv;
    r += __shfl_xor(r, 1);
    r += __shfl_xor(r, 2);
    r += __shfl_xor(r, 4);
    r += __shfl_xor(r, 8);
    if (n == 0) {
      float zv = zp[(size_t)t * (2 * DINNER)];
      float sig = 1.f / (1.f + __expf(-zv));
      yp[(size_t)t * DINNER] = (r + uv * Dv) * (zv * sig);
    }
  }
}

// ---------------- LayerNorm (optional residual add), row = 512 ----------------
__global__ __launch_bounds__(64) void ln_kernel(
    const float* __restrict__ res, const float* __restrict__ add,
    long long add_bstride, long long add_off,
    const float* __restrict__ g, const float* __restrict__ be,
    float* __restrict__ out) {
  int r = blockIdx.x;
  int b = r >> 9, t = r & 511;
  int lane = threadIdx.x;
  const float* rp = res + (size_t)r * DMODEL;
  const float* ap = add ? add + (size_t)b * add_bstride + add_off + (size_t)t * DMODEL
                        : nullptr;
  float v[8];
  float s = 0.f, ss = 0.f;
#pragma unroll
  for (int j = 0; j < 8; ++j) {
    float x = rp[lane + j * 64];
    if (ap) x += ap[lane + j * 64];
    v[j] = x; s += x; ss += x * x;
  }
#pragma unroll
  for (int o = 32; o > 0; o >>= 1) { s += __shfl_xor(s, o); ss += __shfl_xor(ss, o); }
  float m = s * (1.f / 512.f);
  float var = ss * (1.f / 512.f) - m * m;
  float rs = rsqrtf(var + 1e-6f);
#pragma unroll
  for (int j = 0; j < 8; ++j) {
    int c = lane + j * 64;
    out[(size_t)r * DMODEL + c] = (v[j] - m) * rs * g[c] + be[c];
  }
}

// ---------------- orchestration ----------------
extern "C" void kernel_launch(void* const* d_in, const int* in_sizes, int n_in,
                              void* d_out, int out_size, void* d_ws, size_t ws_size,
                              hipStream_t stream) {
  (void)in_sizes; (void)n_in; (void)out_size; (void)ws_size;
  const float* src      = (const float*)d_in[0];
  const int*   tgt      = (const int*)d_in[1];
  const float* emb      = (const float*)d_in[2];
  const float* in_w_s   = (const float*)d_in[3];
  const float* conv_w_s = (const float*)d_in[4];
  const float* conv_b_s = (const float*)d_in[5];
  const float* xproj_s  = (const float*)d_in[6];
  const float* dtw_s    = (const float*)d_in[7];
  const float* dtb_s    = (const float*)d_in[8];
  const float* Alog_s   = (const float*)d_in[9];
  const float* D_s      = (const float*)d_in[10];
  const float* outw_s   = (const float*)d_in[11];
  const float* in_w_c   = (const float*)d_in[12];
  const float* conv_w_c = (const float*)d_in[13];
  const float* conv_b_c = (const float*)d_in[14];
  const float* xproj_c  = (const float*)d_in[15];
  const float* dtw_c    = (const float*)d_in[16];
  const float* dtb_c    = (const float*)d_in[17];
  const float* Alog_c   = (const float*)d_in[18];
  const float* D_c      = (const float*)d_in[19];
  const float* outw_c   = (const float*)d_in[20];
  const float* ffn_w1   = (const float*)d_in[21];
  const float* ffn_b1   = (const float*)d_in[22];
  const float* ffn_w2   = (const float*)d_in[23];
  const float* ffn_b2   = (const float*)d_in[24];
  const float* ln_g     = (const float*)d_in[25];
  const float* ln_b     = (const float*)d_in[26];
  const float* fin_g    = (const float*)d_in[27];
  const float* fin_b    = (const float*)d_in[28];

  float* ws  = (float*)d_ws;
  float* X   = ws;                    // 524288   (2,512,512)
  float* CAT = X + 524288;            // 1048576  (2,1024,512)  (also scan HIN scratch)
  float* XZ  = CAT + 1048576;         // 4194304  (2,1024,2048) (reused as FFN hidden)
  float* XC  = XZ + 4194304;          // 2097152  (2,1024,1024)
  float* DT  = XC + 2097152;          // 2097152  (2,1024,1024) (also split-K scratch)
  float* DBL = DT + 2097152;          // 131072   (2,1024,64)
  float* YS  = DBL + 131072;          // 2097152  (2,1024,1024)
  float* T2  = YS + 2097152;          // 1048576  (2,1024,512)  (also scan P/S scratch)

  float* SC_P   = T2;                 // 524288 = NCHUNK*32768
  float* SC_S   = T2 + 524288;        // 524288
  float* SC_HIN = CAT;                // 524288 (CAT dead at scan time)

  embed_kernel<<<2048, 256, 0, stream>>>(tgt, emb, X);

  for (int i = 0; i < NLAYERS; ++i) {
    // ---------- self mamba (L = 512, CL = 32) ----------
    mgemm128<0><<<dim3(16, 8), 256, 0, stream>>>(
        X, in_w_s + (size_t)i * 1048576, nullptr, XZ, 1024, 2048, 512, 512);
    conv_silu_kernel<<<4096, 256, 0, stream>>>(
        XZ, conv_w_s + (size_t)i * 4096, conv_b_s + (size_t)i * 1024, XC, 512);
    gemm64_split<<<dim3(1, 16, 8), 256, 0, stream>>>(
        XC, xproj_s + (size_t)i * 65536, DT /*scratch*/, 1024, 64, 1024, 1024);
    reduce_sum_kernel<<<256, 256, 0, stream>>>(DT, DBL, 65536, 8);
    mgemm64<3><<<dim3(16, 16), 256, 0, stream>>>(
        DBL, dtw_s + (size_t)i * 32768, dtb_s + (size_t)i * 1024, DT, 1024, 1024, 32, 64);
    scan_pass1<<<dim3(128, NCHUNK), 256, 0, stream>>>(
        DT, DBL, XC, Alog_s + (size_t)i * 16384, SC_P, SC_S, 512, 512 / NCHUNK);
    scan_mid<<<128, 256, 0, stream>>>(SC_P, SC_S, SC_HIN, NCHUNK);
    scan_pass2<<<dim3(128, NCHUNK), 256, 0, stream>>>(
        DT, DBL, XC, XZ, Alog_s + (size_t)i * 16384, D_s + (size_t)i * 1024,
        SC_HIN, YS, 512, 512 / NCHUNK);
    mgemm64<0><<<dim3(8, 16), 256, 0, stream>>>(
        YS, outw_s + (size_t)i * 524288, nullptr, T2, 1024, 512, 1024, 1024);
    ln_kernel<<<1024, 64, 0, stream>>>(
        X, T2, (long long)512 * 512, 0, ln_g + (size_t)(i * 3 + 0) * 512,
        ln_b + (size_t)(i * 3 + 0) * 512, X);

    // ---------- cross mamba (L = 1024, CL = 64) ----------
    concat_kernel<<<1024, 256, 0, stream>>>(src, X, CAT);
    mgemm128<0><<<dim3(16, 16), 256, 0, stream>>>(
        CAT, in_w_c + (size_t)i * 1048576, nullptr, XZ, 2048, 2048, 512, 512);
    conv_silu_kernel<<<8192, 256, 0, stream>>>(
        XZ, conv_w_c + (size_t)i * 4096, conv_b_c + (size_t)i * 1024, XC, 1024);
    gemm64_split<<<dim3(1, 32, 8), 256, 0, stream>>>(
        XC, xproj_c + (size_t)i * 65536, DT /*scratch*/, 2048, 64, 1024, 1024);
    reduce_sum_kernel<<<512, 256, 0, stream>>>(DT, DBL, 131072, 8);
    mgemm64<3><<<dim3(16, 32), 256, 0, stream>>>(
        DBL, dtw_c + (size_t)i * 32768, dtb_c + (size_t)i * 1024, DT, 2048, 1024, 32, 64);
    scan_pass1<<<dim3(128, NCHUNK), 256, 0, stream>>>(
        DT, DBL, XC, Alog_c + (size_t)i * 16384, SC_P, SC_S, 1024, 1024 / NCHUNK);
    scan_mid<<<128, 256, 0, stream>>>(SC_P, SC_S, SC_HIN, NCHUNK);
    scan_pass2<<<dim3(128, NCHUNK), 256, 0, stream>>>(
        DT, DBL, XC, XZ, Alog_c + (size_t)i * 16384, D_c + (size_t)i * 1024,
        SC_HIN, YS, 1024, 1024 / NCHUNK);
    mgemm64<0><<<dim3(8, 32), 256, 0, stream>>>(
        YS, outw_c + (size_t)i * 524288, nullptr, T2, 2048, 512, 1024, 1024);
    ln_kernel<<<1024, 64, 0, stream>>>(
        X, T2, (long long)1024 * 512, (long long)512 * 512,
        ln_g + (size_t)(i * 3 + 1) * 512, ln_b + (size_t)(i * 3 + 1) * 512, X);

    // ---------- FFN ----------
    mgemm128<1><<<dim3(16, 8), 256, 0, stream>>>(
        X, ffn_w1 + (size_t)i * 1048576, ffn_b1 + (size_t)i * 2048, XZ, 1024, 2048, 512, 512);
    mgemm64<2><<<dim3(8, 16), 256, 0, stream>>>(
        XZ, ffn_w2 + (size_t)i * 1048576, ffn_b2 + (size_t)i * 512, T2, 1024, 512, 2048, 2048);
    ln_kernel<<<1024, 64, 0, stream>>>(
        X, T2, (long long)512 * 512, 0, ln_g + (size_t)(i * 3 + 2) * 512,
        ln_b + (size_t)(i * 3 + 2) * 512, X);
  }

  ln_kernel<<<1024, 64, 0, stream>>>(
      X, nullptr, 0, 0, fin_g, fin_b, (float*)d_out);
}

// Round 4
// 1775.648 us; speedup vs baseline: 3.6118x; 1.3604x over previous
//
#include <hip/hip_runtime.h>
#include <math.h>

#define DMODEL 512
#define DINNER 1024
#define DSTATE 16
#define DTRANK 32
#define NLAYERS 6
#define BB 2
#define LT 512
#define LS 512
#define NCHUNK 16

typedef __attribute__((ext_vector_type(8))) short bf16x8;
typedef __attribute__((ext_vector_type(4))) float f32x4;

// fp32 -> bf16 round-to-nearest-even
__device__ __forceinline__ unsigned short f2bf(float f) {
  unsigned u = __float_as_uint(f);
  u += 0x7fffu + ((u >> 16) & 1u);
  return (unsigned short)(u >> 16);
}

// ---------------- epilogues ----------------
// 0=none, 1=bias+relu, 2=bias, 3=bias+softplus
template<int EPI>
__device__ __forceinline__ float epi_apply(float acc, float b) {
  if (EPI == 1) { float v = acc + b; return v > 0.f ? v : 0.f; }
  if (EPI == 2) { return acc + b; }
  if (EPI == 3) { float v = acc + b; return fmaxf(v, 0.f) + log1pf(__expf(-fabsf(v))); }
  return acc;
}

// ---------------- embedding + sinusoidal PE ----------------
__global__ __launch_bounds__(256) void embed_kernel(const int* __restrict__ tgt,
    const float* __restrict__ emb, float* __restrict__ X) {
  int i = blockIdx.x * 256 + threadIdx.x;
  int d = i & (DMODEL - 1);
  int bt = i >> 9;
  int t = bt & (LT - 1);
  int tok = tgt[bt];
  float div = __expf((float)(d & ~1) * (-9.210340371976184f / (float)DMODEL));
  float ang = (float)t * div;
  float pe = (d & 1) ? cosf(ang) : sinf(ang);
  X[i] = emb[(size_t)tok * DMODEL + d] * 22.627416997969522f + pe;
}

// ---------------- concat [src, x] along time ----------------
__global__ __launch_bounds__(256) void concat_kernel(const float* __restrict__ src,
    const float* __restrict__ X, float* __restrict__ CAT) {
  int i = blockIdx.x * 256 + threadIdx.x;
  int c = i & 127;
  int r = i >> 7;
  int l = r & 1023;
  int b = r >> 10;
  const float* s = (l < LS) ? (src + ((size_t)b * LS + l) * DMODEL)
                            : (X + ((size_t)b * LT + (l - LS)) * DMODEL);
  ((float4*)CAT)[(size_t)r * 128 + c] = ((const float4*)s)[c];
}

// ---------------- unified MFMA GEMM: C[M,N] = A[M,K] * Bw[N,K]^T ----------------
// 64x64 tile, BK=32, 4 waves (2x2), 32x32 per wave (2x2 frags of 16x16x32).
// Register-pipelined staging: next tile's global loads issued before compute.
// SPLIT: gridDim.z-way K-split, fp32 partials to C (+z*M*N), no epilogue.
template<int EPI, bool SPLIT>
__global__ __launch_bounds__(256) void mgemm(
    const float* __restrict__ A, const float* __restrict__ Bw,
    const float* __restrict__ bias, float* __restrict__ C,
    int M, int N, int K, int lda) {
  __shared__ unsigned short As[64 * 40];
  __shared__ unsigned short Bs[64 * 40];
  const int tid = threadIdx.x;
  const int bn = blockIdx.x * 64;
  const int bm = blockIdx.y * 64;
  const int lane = tid & 63;
  const int w = tid >> 6;
  const int wr = (w >> 1) * 32;
  const int wc = (w & 1) * 32;
  const int l15 = lane & 15;
  const int l4 = lane >> 4;
  const int koff = l4 * 8;
  int kcnt = K, kbeg = 0;
  if (SPLIT) { kcnt = K / (int)gridDim.z; kbeg = blockIdx.z * kcnt; }
  const int nt = kcnt >> 5;
  f32x4 acc[2][2] = {};

  // per-thread staging map: 2 chunks per operand (64 rows x 8 ushort4-chunks)
  int row_[2], k4_[2];
  const float *Ap[2], *Bp[2];
#pragma unroll
  for (int i = 0; i < 2; ++i) {
    int f = tid + 256 * i;
    row_[i] = f >> 3;
    k4_[i] = (f & 7) * 4;
    Ap[i] = A + (size_t)(bm + row_[i]) * lda + kbeg + k4_[i];
    Bp[i] = Bw + (size_t)(bn + row_[i]) * K + kbeg + k4_[i];
  }

  float4 av[2], bv[2];
#pragma unroll
  for (int i = 0; i < 2; ++i) { av[i] = *(const float4*)Ap[i]; bv[i] = *(const float4*)Bp[i]; }

  for (int t = 0; t < nt; ++t) {
    __syncthreads();
#pragma unroll
    for (int i = 0; i < 2; ++i) {
      *(ushort4*)&As[row_[i] * 40 + k4_[i]] =
          make_ushort4(f2bf(av[i].x), f2bf(av[i].y), f2bf(av[i].z), f2bf(av[i].w));
      *(ushort4*)&Bs[row_[i] * 40 + k4_[i]] =
          make_ushort4(f2bf(bv[i].x), f2bf(bv[i].y), f2bf(bv[i].z), f2bf(bv[i].w));
    }
    if (t + 1 < nt) {
      int ko = (t + 1) * 32;
#pragma unroll
      for (int i = 0; i < 2; ++i) {
        av[i] = *(const float4*)(Ap[i] + ko);
        bv[i] = *(const float4*)(Bp[i] + ko);
      }
    }
    __syncthreads();
    bf16x8 afr[2], bfr[2];
#pragma unroll
    for (int i = 0; i < 2; ++i) {
      afr[i] = *(const bf16x8*)&As[(wr + i * 16 + l15) * 40 + koff];
      bfr[i] = *(const bf16x8*)&Bs[(wc + i * 16 + l15) * 40 + koff];
    }
#pragma unroll
    for (int fr = 0; fr < 2; ++fr)
#pragma unroll
      for (int fc = 0; fc < 2; ++fc)
        acc[fr][fc] = __builtin_amdgcn_mfma_f32_16x16x32_bf16(
            afr[fr], bfr[fc], acc[fr][fc], 0, 0, 0);
  }

  if (SPLIT) {
    float* Pz = C + (size_t)blockIdx.z * M * N;
#pragma unroll
    for (int fc = 0; fc < 2; ++fc) {
      int col = bn + wc + fc * 16 + l15;
#pragma unroll
      for (int fr = 0; fr < 2; ++fr) {
        int row0 = bm + wr + fr * 16 + l4 * 4;
#pragma unroll
        for (int r = 0; r < 4; ++r)
          Pz[(size_t)(row0 + r) * N + col] = acc[fr][fc][r];
      }
    }
  } else {
#pragma unroll
    for (int fc = 0; fc < 2; ++fc) {
      int col = bn + wc + fc * 16 + l15;
      float bvs = (EPI != 0) ? bias[col] : 0.f;
#pragma unroll
      for (int fr = 0; fr < 2; ++fr) {
        int row0 = bm + wr + fr * 16 + l4 * 4;
#pragma unroll
        for (int r = 0; r < 4; ++r)
          C[(size_t)(row0 + r) * N + col] = epi_apply<EPI>(acc[fr][fc][r], bvs);
      }
    }
  }
}

// ---------------- split-K reduction with epilogue ----------------
template<int EPI>
__global__ __launch_bounds__(256) void reduce_epi_kernel(
    const float* __restrict__ P, const float* __restrict__ bias,
    float* __restrict__ C, int total, int nz, int nmask) {
  int i = blockIdx.x * 256 + threadIdx.x;
  if (i >= total) return;
  float s = 0.f;
  for (int z = 0; z < nz; ++z) s += P[(size_t)z * total + i];
  float b = (EPI != 0) ? bias[i & nmask] : 0.f;
  C[i] = epi_apply<EPI>(s, b);
}

// ---------------- causal depthwise conv (k=4) + bias + silu ----------------
__global__ __launch_bounds__(256) void conv_silu_kernel(
    const float* __restrict__ xz, const float* __restrict__ w,
    const float* __restrict__ bias, float* __restrict__ out, int L) {
  int idx = blockIdx.x * 256 + threadIdx.x;
  int d = idx & (DINNER - 1);
  int bt = idx >> 10;
  int b = bt / L;
  int t = bt - b * L;
  const float* col = xz + ((size_t)b * L) * (2 * DINNER) + d;
  float acc = bias[d];
#pragma unroll
  for (int k = 0; k < 4; ++k) {
    int tt = t - 3 + k;
    if (tt >= 0) acc = fmaf(col[(size_t)tt * (2 * DINNER)], w[d * 4 + k], acc);
  }
  float sig = 1.f / (1.f + __expf(-acc));
  out[idx] = acc * sig;
}

// ---------------- chunked selective scan ----------------
__global__ __launch_bounds__(256) void scan_pass1(
    const float* __restrict__ dt, const float* __restrict__ dbl,
    const float* __restrict__ u, const float* __restrict__ Alog,
    float* __restrict__ P, float* __restrict__ S, int L, int CL) {
  int s = blockIdx.x * 256 + threadIdx.x;
  int n = s & 15;
  int d = (s >> 4) & 1023;
  int b = s >> 14;
  int c = blockIdx.y;
  int t0 = c * CL;
  float A = -__expf(Alog[d * DSTATE + n]);
  const float* dtp = dt + ((size_t)b * L + t0) * DINNER + d;
  const float* up  = u  + ((size_t)b * L + t0) * DINNER + d;
  const float* Bp  = dbl + ((size_t)b * L + t0) * 64 + DTRANK + n;
  float h = 0.f, Pp = 1.f;
  for (int t = 0; t < CL; ++t) {
    float dtv = dtp[(size_t)t * DINNER];
    float uv  = up[(size_t)t * DINNER];
    float Bv  = Bp[(size_t)t * 64];
    float dA = __expf(dtv * A);
    Pp *= dA;
    h = fmaf(dA, h, dtv * uv * Bv);
  }
  P[(size_t)c * 32768 + s] = Pp;
  S[(size_t)c * 32768 + s] = h;
}

__global__ __launch_bounds__(256) void scan_mid(
    const float* __restrict__ P, const float* __restrict__ S,
    float* __restrict__ HIN, int C) {
  int s = blockIdx.x * 256 + threadIdx.x;
  float h = 0.f;
  for (int c = 0; c < C; ++c) {
    HIN[(size_t)c * 32768 + s] = h;
    h = fmaf(P[(size_t)c * 32768 + s], h, S[(size_t)c * 32768 + s]);
  }
}

__global__ __launch_bounds__(256) void scan_pass2(
    const float* __restrict__ dt, const float* __restrict__ dbl,
    const float* __restrict__ u, const float* __restrict__ xz,
    const float* __restrict__ Alog, const float* __restrict__ Dsk,
    const float* __restrict__ HIN, float* __restrict__ ys, int L, int CL) {
  int tid = threadIdx.x;
  int g = tid >> 4, n = tid & 15;
  int chan = blockIdx.x * 16 + g;
  int b = chan >> 10, d = chan & 1023;
  int c = blockIdx.y;
  int t0 = c * CL;
  int s = (chan << 4) | n;
  float A = -__expf(Alog[d * DSTATE + n]);
  float Dv = Dsk[d];
  const float* dtp = dt + ((size_t)b * L + t0) * DINNER + d;
  const float* up  = u  + ((size_t)b * L + t0) * DINNER + d;
  const float* zp  = xz + ((size_t)b * L + t0) * (2 * DINNER) + DINNER + d;
  const float* Bp  = dbl + ((size_t)b * L + t0) * 64 + DTRANK + n;
  const float* Cp  = Bp + DSTATE;
  float* yp = ys + ((size_t)b * L + t0) * DINNER + d;
  float h = HIN[(size_t)c * 32768 + s];
  for (int t = 0; t < CL; ++t) {
    float dtv = dtp[(size_t)t * DINNER];
    float uv  = up[(size_t)t * DINNER];
    float Bv  = Bp[(size_t)t * 64];
    float Cv  = Cp[(size_t)t * 64];
    float dA = __expf(dtv * A);
    h = fmaf(dA, h, dtv * uv * Bv);
    float r = h * Cv;
    r += __shfl_xor(r, 1);
    r += __shfl_xor(r, 2);
    r += __shfl_xor(r, 4);
    r += __shfl_xor(r, 8);
    if (n == 0) {
      float zv = zp[(size_t)t * (2 * DINNER)];
      float sig = 1.f / (1.f + __expf(-zv));
      yp[(size_t)t * DINNER] = (r + uv * Dv) * (zv * sig);
    }
  }
}

// ---------------- LayerNorm (optional residual add), row = 512 ----------------
__global__ __launch_bounds__(64) void ln_kernel(
    const float* __restrict__ res, const float* __restrict__ add,
    long long add_bstride, long long add_off,
    const float* __restrict__ g, const float* __restrict__ be,
    float* __restrict__ out) {
  int r = blockIdx.x;
  int b = r >> 9, t = r & 511;
  int lane = threadIdx.x;
  const float* rp = res + (size_t)r * DMODEL;
  const float* ap = add ? add + (size_t)b * add_bstride + add_off + (size_t)t * DMODEL
                        : nullptr;
  float v[8];
  float s = 0.f, ss = 0.f;
#pragma unroll
  for (int j = 0; j < 8; ++j) {
    float x = rp[lane + j * 64];
    if (ap) x += ap[lane + j * 64];
    v[j] = x; s += x; ss += x * x;
  }
#pragma unroll
  for (int o = 32; o > 0; o >>= 1) { s += __shfl_xor(s, o); ss += __shfl_xor(ss, o); }
  float m = s * (1.f / 512.f);
  float var = ss * (1.f / 512.f) - m * m;
  float rs = rsqrtf(var + 1e-6f);
#pragma unroll
  for (int j = 0; j < 8; ++j) {
    int c = lane + j * 64;
    out[(size_t)r * DMODEL + c] = (v[j] - m) * rs * g[c] + be[c];
  }
}

// ---------------- orchestration ----------------
extern "C" void kernel_launch(void* const* d_in, const int* in_sizes, int n_in,
                              void* d_out, int out_size, void* d_ws, size_t ws_size,
                              hipStream_t stream) {
  (void)in_sizes; (void)n_in; (void)out_size; (void)ws_size;
  const float* src      = (const float*)d_in[0];
  const int*   tgt      = (const int*)d_in[1];
  const float* emb      = (const float*)d_in[2];
  const float* in_w_s   = (const float*)d_in[3];
  const float* conv_w_s = (const float*)d_in[4];
  const float* conv_b_s = (const float*)d_in[5];
  const float* xproj_s  = (const float*)d_in[6];
  const float* dtw_s    = (const float*)d_in[7];
  const float* dtb_s    = (const float*)d_in[8];
  const float* Alog_s   = (const float*)d_in[9];
  const float* D_s      = (const float*)d_in[10];
  const float* outw_s   = (const float*)d_in[11];
  const float* in_w_c   = (const float*)d_in[12];
  const float* conv_w_c = (const float*)d_in[13];
  const float* conv_b_c = (const float*)d_in[14];
  const float* xproj_c  = (const float*)d_in[15];
  const float* dtw_c    = (const float*)d_in[16];
  const float* dtb_c    = (const float*)d_in[17];
  const float* Alog_c   = (const float*)d_in[18];
  const float* D_c      = (const float*)d_in[19];
  const float* outw_c   = (const float*)d_in[20];
  const float* ffn_w1   = (const float*)d_in[21];
  const float* ffn_b1   = (const float*)d_in[22];
  const float* ffn_w2   = (const float*)d_in[23];
  const float* ffn_b2   = (const float*)d_in[24];
  const float* ln_g     = (const float*)d_in[25];
  const float* ln_b     = (const float*)d_in[26];
  const float* fin_g    = (const float*)d_in[27];
  const float* fin_b    = (const float*)d_in[28];

  float* ws  = (float*)d_ws;
  float* X   = ws;                    // 524288   (2,512,512)
  float* CAT = X + 524288;            // 1048576  (2,1024,512)  (also scan HIN scratch)
  float* XZ  = CAT + 1048576;         // 4194304  (2,1024,2048) (reused as FFN hidden)
  float* XC  = XZ + 4194304;          // 2097152  (2,1024,1024) (also split-K partials)
  float* DT  = XC + 2097152;          // 2097152  (2,1024,1024) (also split-K partials)
  float* DBL = DT + 2097152;          // 131072   (2,1024,64)
  float* YS  = DBL + 131072;          // 2097152  (2,1024,1024)
  float* T2  = YS + 2097152;          // 1048576  (2,1024,512)  (also scan P/S scratch)

  float* SC_P   = T2;                 // 524288 = NCHUNK*32768
  float* SC_S   = T2 + 524288;        // 524288
  float* SC_HIN = CAT;                // 524288 (CAT dead at scan time)

  embed_kernel<<<2048, 256, 0, stream>>>(tgt, emb, X);

  for (int i = 0; i < NLAYERS; ++i) {
    // ---------- self mamba (L = 512, CL = 32) ----------
    mgemm<0, false><<<dim3(32, 16), 256, 0, stream>>>(
        X, in_w_s + (size_t)i * 1048576, nullptr, XZ, 1024, 2048, 512, 512);
    conv_silu_kernel<<<4096, 256, 0, stream>>>(
        XZ, conv_w_s + (size_t)i * 4096, conv_b_s + (size_t)i * 1024, XC, 512);
    mgemm<0, true><<<dim3(1, 16, 8), 256, 0, stream>>>(
        XC, xproj_s + (size_t)i * 65536, nullptr, DT /*partials*/, 1024, 64, 1024, 1024);
    reduce_epi_kernel<0><<<256, 256, 0, stream>>>(DT, nullptr, DBL, 65536, 8, 0);
    mgemm<3, false><<<dim3(16, 16), 256, 0, stream>>>(
        DBL, dtw_s + (size_t)i * 32768, dtb_s + (size_t)i * 1024, DT, 1024, 1024, 32, 64);
    scan_pass1<<<dim3(128, NCHUNK), 256, 0, stream>>>(
        DT, DBL, XC, Alog_s + (size_t)i * 16384, SC_P, SC_S, 512, 512 / NCHUNK);
    scan_mid<<<128, 256, 0, stream>>>(SC_P, SC_S, SC_HIN, NCHUNK);
    scan_pass2<<<dim3(128, NCHUNK), 256, 0, stream>>>(
        DT, DBL, XC, XZ, Alog_s + (size_t)i * 16384, D_s + (size_t)i * 1024,
        SC_HIN, YS, 512, 512 / NCHUNK);
    mgemm<0, true><<<dim3(8, 16, 4), 256, 0, stream>>>(
        YS, outw_s + (size_t)i * 524288, nullptr, XC /*partials*/, 1024, 512, 1024, 1024);
    reduce_epi_kernel<0><<<2048, 256, 0, stream>>>(XC, nullptr, T2, 524288, 4, 0);
    ln_kernel<<<1024, 64, 0, stream>>>(
        X, T2, (long long)512 * 512, 0, ln_g + (size_t)(i * 3 + 0) * 512,
        ln_b + (size_t)(i * 3 + 0) * 512, X);

    // ---------- cross mamba (L = 1024, CL = 64) ----------
    concat_kernel<<<1024, 256, 0, stream>>>(src, X, CAT);
    mgemm<0, false><<<dim3(32, 32), 256, 0, stream>>>(
        CAT, in_w_c + (size_t)i * 1048576, nullptr, XZ, 2048, 2048, 512, 512);
    conv_silu_kernel<<<8192, 256, 0, stream>>>(
        XZ, conv_w_c + (size_t)i * 4096, conv_b_c + (size_t)i * 1024, XC, 1024);
    mgemm<0, true><<<dim3(1, 32, 8), 256, 0, stream>>>(
        XC, xproj_c + (size_t)i * 65536, nullptr, DT /*partials*/, 2048, 64, 1024, 1024);
    reduce_epi_kernel<0><<<512, 256, 0, stream>>>(DT, nullptr, DBL, 131072, 8, 0);
    mgemm<3, false><<<dim3(16, 32), 256, 0, stream>>>(
        DBL, dtw_c + (size_t)i * 32768, dtb_c + (size_t)i * 1024, DT, 2048, 1024, 32, 64);
    scan_pass1<<<dim3(128, NCHUNK), 256, 0, stream>>>(
        DT, DBL, XC, Alog_c + (size_t)i * 16384, SC_P, SC_S, 1024, 1024 / NCHUNK);
    scan_mid<<<128, 256, 0, stream>>>(SC_P, SC_S, SC_HIN, NCHUNK);
    scan_pass2<<<dim3(128, NCHUNK), 256, 0, stream>>>(
        DT, DBL, XC, XZ, Alog_c + (size_t)i * 16384, D_c + (size_t)i * 1024,
        SC_HIN, YS, 1024, 1024 / NCHUNK);
    mgemm<0, true><<<dim3(8, 32, 4), 256, 0, stream>>>(
        YS, outw_c + (size_t)i * 524288, nullptr, XC /*partials (XC+DT, 4M)*/, 2048, 512, 1024, 1024);
    reduce_epi_kernel<0><<<4096, 256, 0, stream>>>(XC, nullptr, T2, 1048576, 4, 0);
    ln_kernel<<<1024, 64, 0, stream>>>(
        X, T2, (long long)1024 * 512, (long long)512 * 512,
        ln_g + (size_t)(i * 3 + 1) * 512, ln_b + (size_t)(i * 3 + 1) * 512, X);

    // ---------- FFN ----------
    mgemm<1, false><<<dim3(32, 16), 256, 0, stream>>>(
        X, ffn_w1 + (size_t)i * 1048576, ffn_b1 + (size_t)i * 2048, XZ, 1024, 2048, 512, 512);
    mgemm<0, true><<<dim3(8, 16, 8), 256, 0, stream>>>(
        XZ, ffn_w2 + (size_t)i * 1048576, nullptr, XC /*partials (XC+DT, 4M)*/, 1024, 512, 2048, 2048);
    reduce_epi_kernel<2><<<2048, 256, 0, stream>>>(
        XC, ffn_b2 + (size_t)i * 512, T2, 524288, 8, 511);
    ln_kernel<<<1024, 64, 0, stream>>>(
        X, T2, (long long)512 * 512, 0, ln_g + (size_t)(i * 3 + 2) * 512,
        ln_b + (size_t)(i * 3 + 2) * 512, X);
  }

  ln_kernel<<<1024, 64, 0, stream>>>(
      X, nullptr, 0, 0, fin_g, fin_b, (float*)d_out);
}

// Round 5
// 1476.347 us; speedup vs baseline: 4.3440x; 1.2027x over previous
//
#include <hip/hip_runtime.h>
#include <math.h>

#define DMODEL 512
#define DINNER 1024
#define DSTATE 16
#define DTRANK 32
#define NLAYERS 6
#define BB 2
#define LT 512
#define LS 512
#define NCHUNK 32

typedef __attribute__((ext_vector_type(8))) short bf16x8;
typedef __attribute__((ext_vector_type(4))) float f32x4;

// fp32 -> bf16 round-to-nearest-even
__device__ __forceinline__ unsigned short f2bf(float f) {
  unsigned u = __float_as_uint(f);
  u += 0x7fffu + ((u >> 16) & 1u);
  return (unsigned short)(u >> 16);
}

// ---------------- epilogues ----------------
// 0=none, 1=bias+relu, 2=bias, 3=bias+softplus
template<int EPI>
__device__ __forceinline__ float epi_apply(float acc, float b) {
  if (EPI == 1) { float v = acc + b; return v > 0.f ? v : 0.f; }
  if (EPI == 2) { return acc + b; }
  if (EPI == 3) { float v = acc + b; return fmaxf(v, 0.f) + log1pf(__expf(-fabsf(v))); }
  return acc;
}

// ---------------- embedding + sinusoidal PE ----------------
__global__ __launch_bounds__(256) void embed_kernel(const int* __restrict__ tgt,
    const float* __restrict__ emb, float* __restrict__ X) {
  int i = blockIdx.x * 256 + threadIdx.x;
  int d = i & (DMODEL - 1);
  int bt = i >> 9;
  int t = bt & (LT - 1);
  int tok = tgt[bt];
  float div = __expf((float)(d & ~1) * (-9.210340371976184f / (float)DMODEL));
  float ang = (float)t * div;
  float pe = (d & 1) ? cosf(ang) : sinf(ang);
  X[i] = emb[(size_t)tok * DMODEL + d] * 22.627416997969522f + pe;
}

// ---------------- concat [src, x] along time ----------------
__global__ __launch_bounds__(256) void concat_kernel(const float* __restrict__ src,
    const float* __restrict__ X, float* __restrict__ CAT) {
  int i = blockIdx.x * 256 + threadIdx.x;
  int c = i & 127;
  int r = i >> 7;
  int l = r & 1023;
  int b = r >> 10;
  const float* s = (l < LS) ? (src + ((size_t)b * LS + l) * DMODEL)
                            : (X + ((size_t)b * LT + (l - LS)) * DMODEL);
  ((float4*)CAT)[(size_t)r * 128 + c] = ((const float4*)s)[c];
}

// ---------------- unified MFMA GEMM: C[M,N] = A[M,K] * Bw[N,K]^T ----------------
// 64x64 tile, BK=32, 4 waves (2x2), 32x32 per wave (2x2 frags of 16x16x32).
// SPLIT: gridDim.z-way K-split, fp32 partials to C (+z*M*N), no epilogue.
template<int EPI, bool SPLIT>
__global__ __launch_bounds__(256) void mgemm(
    const float* __restrict__ A, const float* __restrict__ Bw,
    const float* __restrict__ bias, float* __restrict__ C,
    int M, int N, int K, int lda) {
  __shared__ unsigned short As[64 * 40];
  __shared__ unsigned short Bs[64 * 40];
  const int tid = threadIdx.x;
  const int bn = blockIdx.x * 64;
  const int bm = blockIdx.y * 64;
  const int lane = tid & 63;
  const int w = tid >> 6;
  const int wr = (w >> 1) * 32;
  const int wc = (w & 1) * 32;
  const int l15 = lane & 15;
  const int l4 = lane >> 4;
  const int koff = l4 * 8;
  int kcnt = K, kbeg = 0;
  if (SPLIT) { kcnt = K / (int)gridDim.z; kbeg = blockIdx.z * kcnt; }
  const int nt = kcnt >> 5;
  f32x4 acc[2][2] = {};

  int row_[2], k4_[2];
  const float *Ap[2], *Bp[2];
#pragma unroll
  for (int i = 0; i < 2; ++i) {
    int f = tid + 256 * i;
    row_[i] = f >> 3;
    k4_[i] = (f & 7) * 4;
    Ap[i] = A + (size_t)(bm + row_[i]) * lda + kbeg + k4_[i];
    Bp[i] = Bw + (size_t)(bn + row_[i]) * K + kbeg + k4_[i];
  }

  float4 av[2], bv[2];
#pragma unroll
  for (int i = 0; i < 2; ++i) { av[i] = *(const float4*)Ap[i]; bv[i] = *(const float4*)Bp[i]; }

  for (int t = 0; t < nt; ++t) {
    __syncthreads();
#pragma unroll
    for (int i = 0; i < 2; ++i) {
      *(ushort4*)&As[row_[i] * 40 + k4_[i]] =
          make_ushort4(f2bf(av[i].x), f2bf(av[i].y), f2bf(av[i].z), f2bf(av[i].w));
      *(ushort4*)&Bs[row_[i] * 40 + k4_[i]] =
          make_ushort4(f2bf(bv[i].x), f2bf(bv[i].y), f2bf(bv[i].z), f2bf(bv[i].w));
    }
    if (t + 1 < nt) {
      int ko = (t + 1) * 32;
#pragma unroll
      for (int i = 0; i < 2; ++i) {
        av[i] = *(const float4*)(Ap[i] + ko);
        bv[i] = *(const float4*)(Bp[i] + ko);
      }
    }
    __syncthreads();
    bf16x8 afr[2], bfr[2];
#pragma unroll
    for (int i = 0; i < 2; ++i) {
      afr[i] = *(const bf16x8*)&As[(wr + i * 16 + l15) * 40 + koff];
      bfr[i] = *(const bf16x8*)&Bs[(wc + i * 16 + l15) * 40 + koff];
    }
#pragma unroll
    for (int fr = 0; fr < 2; ++fr)
#pragma unroll
      for (int fc = 0; fc < 2; ++fc)
        acc[fr][fc] = __builtin_amdgcn_mfma_f32_16x16x32_bf16(
            afr[fr], bfr[fc], acc[fr][fc], 0, 0, 0);
  }

  if (SPLIT) {
    float* Pz = C + (size_t)blockIdx.z * M * N;
#pragma unroll
    for (int fc = 0; fc < 2; ++fc) {
      int col = bn + wc + fc * 16 + l15;
#pragma unroll
      for (int fr = 0; fr < 2; ++fr) {
        int row0 = bm + wr + fr * 16 + l4 * 4;
#pragma unroll
        for (int r = 0; r < 4; ++r)
          Pz[(size_t)(row0 + r) * N + col] = acc[fr][fc][r];
      }
    }
  } else {
#pragma unroll
    for (int fc = 0; fc < 2; ++fc) {
      int col = bn + wc + fc * 16 + l15;
      float bvs = (EPI != 0) ? bias[col] : 0.f;
#pragma unroll
      for (int fr = 0; fr < 2; ++fr) {
        int row0 = bm + wr + fr * 16 + l4 * 4;
#pragma unroll
        for (int r = 0; r < 4; ++r)
          C[(size_t)(row0 + r) * N + col] = epi_apply<EPI>(acc[fr][fc][r], bvs);
      }
    }
  }
}

// ---------------- split-K reduction with epilogue ----------------
template<int EPI>
__global__ __launch_bounds__(256) void reduce_epi_kernel(
    const float* __restrict__ P, const float* __restrict__ bias,
    float* __restrict__ C, int total, int nz, int nmask) {
  int i = blockIdx.x * 256 + threadIdx.x;
  if (i >= total) return;
  float s = 0.f;
  for (int z = 0; z < nz; ++z) s += P[(size_t)z * total + i];
  float b = (EPI != 0) ? bias[i & nmask] : 0.f;
  C[i] = epi_apply<EPI>(s, b);
}

// ---------------- causal depthwise conv (k=4) + bias + silu ----------------
__global__ __launch_bounds__(256) void conv_silu_kernel(
    const float* __restrict__ xz, const float* __restrict__ w,
    const float* __restrict__ bias, float* __restrict__ out, int L) {
  int idx = blockIdx.x * 256 + threadIdx.x;
  int d = idx & (DINNER - 1);
  int bt = idx >> 10;
  int b = bt / L;
  int t = bt - b * L;
  const float* col = xz + ((size_t)b * L) * (2 * DINNER) + d;
  float acc = bias[d];
#pragma unroll
  for (int k = 0; k < 4; ++k) {
    int tt = t - 3 + k;
    if (tt >= 0) acc = fmaf(col[(size_t)tt * (2 * DINNER)], w[d * 4 + k], acc);
  }
  float sig = 1.f / (1.f + __expf(-acc));
  out[idx] = acc * sig;
}

// ---------------- chunked selective scan, lane = one (b,d) channel ----------------
// 16 n-states live in registers. B/C staged in LDS (broadcast reads).
// grid: (DINNER/256, BB, NCHUNK); P/S layout [c][(b*1024+d)*16+n].
__global__ __launch_bounds__(256) void scan_pass1(
    const float* __restrict__ dt, const float* __restrict__ dbl,
    const float* __restrict__ u, const float* __restrict__ Alog,
    float* __restrict__ P, float* __restrict__ S, int L, int CL) {
  __shared__ float BC[32][32];
  const int tid = threadIdx.x;
  const int d = blockIdx.x * 256 + tid;
  const int b = blockIdx.y;
  const int c = blockIdx.z;
  const int t0 = c * CL;
  // stage B,C (cols 32..63 of dbl rows t0..t0+CL-1)
  if (tid < CL * 8) {
    int t = tid >> 3, j4 = (tid & 7) * 4;
    *(float4*)&BC[t][j4] = *(const float4*)(dbl + ((size_t)b * L + t0 + t) * 64 + 32 + j4);
  }
  float A[16], h[16], Pp[16];
#pragma unroll
  for (int j = 0; j < 4; ++j) {
    float4 a4 = *(const float4*)(Alog + d * 16 + j * 4);
    A[j * 4 + 0] = -__expf(a4.x); A[j * 4 + 1] = -__expf(a4.y);
    A[j * 4 + 2] = -__expf(a4.z); A[j * 4 + 3] = -__expf(a4.w);
  }
#pragma unroll
  for (int n = 0; n < 16; ++n) { h[n] = 0.f; Pp[n] = 1.f; }
  const float* dtp = dt + ((size_t)b * L + t0) * DINNER + d;
  const float* up  = u  + ((size_t)b * L + t0) * DINNER + d;
  __syncthreads();
  float dtv = dtp[0], uv = up[0];
  for (int t = 0; t < CL; ++t) {
    float dtn = 0.f, un = 0.f;
    if (t + 1 < CL) { dtn = dtp[(size_t)(t + 1) * DINNER]; un = up[(size_t)(t + 1) * DINNER]; }
    float du = dtv * uv;
    float Bv[16];
#pragma unroll
    for (int j = 0; j < 4; ++j) {
      float4 b4 = *(const float4*)&BC[t][j * 4];
      Bv[j * 4 + 0] = b4.x; Bv[j * 4 + 1] = b4.y; Bv[j * 4 + 2] = b4.z; Bv[j * 4 + 3] = b4.w;
    }
#pragma unroll
    for (int n = 0; n < 16; ++n) {
      float dA = __expf(dtv * A[n]);
      Pp[n] *= dA;
      h[n] = fmaf(dA, h[n], du * Bv[n]);
    }
    dtv = dtn; uv = un;
  }
  size_t base = (size_t)c * 32768 + ((size_t)(b * 1024 + d) << 4);
#pragma unroll
  for (int j = 0; j < 4; ++j) {
    *(float4*)&P[base + j * 4] = make_float4(Pp[j*4], Pp[j*4+1], Pp[j*4+2], Pp[j*4+3]);
    *(float4*)&S[base + j * 4] = make_float4(h[j*4], h[j*4+1], h[j*4+2], h[j*4+3]);
  }
}

// serial scan over chunks -> h_in per chunk (HIN may alias P: read-before-write)
__global__ __launch_bounds__(256) void scan_mid(
    const float* __restrict__ P, const float* __restrict__ S,
    float* __restrict__ HIN, int C) {
  int s = blockIdx.x * 256 + threadIdx.x;
  float h = 0.f;
  for (int c = 0; c < C; ++c) {
    float p = P[(size_t)c * 32768 + s];
    float sv = S[(size_t)c * 32768 + s];
    HIN[(size_t)c * 32768 + s] = h;
    h = fmaf(p, h, sv);
  }
}

__global__ __launch_bounds__(256) void scan_pass2(
    const float* __restrict__ dt, const float* __restrict__ dbl,
    const float* __restrict__ u, const float* __restrict__ xz,
    const float* __restrict__ Alog, const float* __restrict__ Dsk,
    const float* __restrict__ HIN, float* __restrict__ ys, int L, int CL) {
  __shared__ float BC[32][32];
  const int tid = threadIdx.x;
  const int d = blockIdx.x * 256 + tid;
  const int b = blockIdx.y;
  const int c = blockIdx.z;
  const int t0 = c * CL;
  if (tid < CL * 8) {
    int t = tid >> 3, j4 = (tid & 7) * 4;
    *(float4*)&BC[t][j4] = *(const float4*)(dbl + ((size_t)b * L + t0 + t) * 64 + 32 + j4);
  }
  float A[16], h[16];
#pragma unroll
  for (int j = 0; j < 4; ++j) {
    float4 a4 = *(const float4*)(Alog + d * 16 + j * 4);
    A[j * 4 + 0] = -__expf(a4.x); A[j * 4 + 1] = -__expf(a4.y);
    A[j * 4 + 2] = -__expf(a4.z); A[j * 4 + 3] = -__expf(a4.w);
  }
  size_t base = (size_t)c * 32768 + ((size_t)(b * 1024 + d) << 4);
#pragma unroll
  for (int j = 0; j < 4; ++j) {
    float4 h4 = *(const float4*)&HIN[base + j * 4];
    h[j * 4 + 0] = h4.x; h[j * 4 + 1] = h4.y; h[j * 4 + 2] = h4.z; h[j * 4 + 3] = h4.w;
  }
  float Dv = Dsk[d];
  const float* dtp = dt + ((size_t)b * L + t0) * DINNER + d;
  const float* up  = u  + ((size_t)b * L + t0) * DINNER + d;
  const float* zp  = xz + ((size_t)b * L + t0) * (2 * DINNER) + DINNER + d;
  float* yp = ys + ((size_t)b * L + t0) * DINNER + d;
  __syncthreads();
  float dtv = dtp[0], uv = up[0], zv = zp[0];
  for (int t = 0; t < CL; ++t) {
    float dtn = 0.f, un = 0.f, zn = 0.f;
    if (t + 1 < CL) {
      dtn = dtp[(size_t)(t + 1) * DINNER];
      un  = up[(size_t)(t + 1) * DINNER];
      zn  = zp[(size_t)(t + 1) * (2 * DINNER)];
    }
    float du = dtv * uv;
    float Bv[16], Cv[16];
#pragma unroll
    for (int j = 0; j < 4; ++j) {
      float4 b4 = *(const float4*)&BC[t][j * 4];
      float4 c4 = *(const float4*)&BC[t][16 + j * 4];
      Bv[j*4+0] = b4.x; Bv[j*4+1] = b4.y; Bv[j*4+2] = b4.z; Bv[j*4+3] = b4.w;
      Cv[j*4+0] = c4.x; Cv[j*4+1] = c4.y; Cv[j*4+2] = c4.z; Cv[j*4+3] = c4.w;
    }
    float y = 0.f;
#pragma unroll
    for (int n = 0; n < 16; ++n) {
      float dA = __expf(dtv * A[n]);
      h[n] = fmaf(dA, h[n], du * Bv[n]);
      y = fmaf(h[n], Cv[n], y);
    }
    float sig = 1.f / (1.f + __expf(-zv));
    yp[(size_t)t * DINNER] = (y + uv * Dv) * (zv * sig);
    dtv = dtn; uv = un; zv = zn;
  }
}

// ---------------- LayerNorm (optional residual add), row = 512 ----------------
__global__ __launch_bounds__(64) void ln_kernel(
    const float* __restrict__ res, const float* __restrict__ add,
    long long add_bstride, long long add_off,
    const float* __restrict__ g, const float* __restrict__ be,
    float* __restrict__ out) {
  int r = blockIdx.x;
  int b = r >> 9, t = r & 511;
  int lane = threadIdx.x;
  const float* rp = res + (size_t)r * DMODEL;
  const float* ap = add ? add + (size_t)b * add_bstride + add_off + (size_t)t * DMODEL
                        : nullptr;
  float v[8];
  float s = 0.f, ss = 0.f;
#pragma unroll
  for (int j = 0; j < 8; ++j) {
    float x = rp[lane + j * 64];
    if (ap) x += ap[lane + j * 64];
    v[j] = x; s += x; ss += x * x;
  }
#pragma unroll
  for (int o = 32; o > 0; o >>= 1) { s += __shfl_xor(s, o); ss += __shfl_xor(ss, o); }
  float m = s * (1.f / 512.f);
  float var = ss * (1.f / 512.f) - m * m;
  float rs = rsqrtf(var + 1e-6f);
#pragma unroll
  for (int j = 0; j < 8; ++j) {
    int c = lane + j * 64;
    out[(size_t)r * DMODEL + c] = (v[j] - m) * rs * g[c] + be[c];
  }
}

// ---------------- orchestration ----------------
extern "C" void kernel_launch(void* const* d_in, const int* in_sizes, int n_in,
                              void* d_out, int out_size, void* d_ws, size_t ws_size,
                              hipStream_t stream) {
  (void)in_sizes; (void)n_in; (void)out_size; (void)ws_size;
  const float* src      = (const float*)d_in[0];
  const int*   tgt      = (const int*)d_in[1];
  const float* emb      = (const float*)d_in[2];
  const float* in_w_s   = (const float*)d_in[3];
  const float* conv_w_s = (const float*)d_in[4];
  const float* conv_b_s = (const float*)d_in[5];
  const float* xproj_s  = (const float*)d_in[6];
  const float* dtw_s    = (const float*)d_in[7];
  const float* dtb_s    = (const float*)d_in[8];
  const float* Alog_s   = (const float*)d_in[9];
  const float* D_s      = (const float*)d_in[10];
  const float* outw_s   = (const float*)d_in[11];
  const float* in_w_c   = (const float*)d_in[12];
  const float* conv_w_c = (const float*)d_in[13];
  const float* conv_b_c = (const float*)d_in[14];
  const float* xproj_c  = (const float*)d_in[15];
  const float* dtw_c    = (const float*)d_in[16];
  const float* dtb_c    = (const float*)d_in[17];
  const float* Alog_c   = (const float*)d_in[18];
  const float* D_c      = (const float*)d_in[19];
  const float* outw_c   = (const float*)d_in[20];
  const float* ffn_w1   = (const float*)d_in[21];
  const float* ffn_b1   = (const float*)d_in[22];
  const float* ffn_w2   = (const float*)d_in[23];
  const float* ffn_b2   = (const float*)d_in[24];
  const float* ln_g     = (const float*)d_in[25];
  const float* ln_b     = (const float*)d_in[26];
  const float* fin_g    = (const float*)d_in[27];
  const float* fin_b    = (const float*)d_in[28];

  float* ws  = (float*)d_ws;
  float* X   = ws;                    // 524288   (2,512,512)
  float* CAT = X + 524288;            // 1048576  (2,1024,512)  (also scan S scratch)
  float* XZ  = CAT + 1048576;         // 4194304  (2,1024,2048) (reused as FFN hidden)
  float* XC  = XZ + 4194304;          // 2097152  (2,1024,1024) (also split-K partials)
  float* DT  = XC + 2097152;          // 2097152  (2,1024,1024) (also split-K partials)
  float* DBL = DT + 2097152;          // 131072   (2,1024,64)
  float* YS  = DBL + 131072;          // 2097152  (2,1024,1024)
  float* T2  = YS + 2097152;          // 1048576  (2,1024,512)  (also scan P/HIN scratch)

  float* SC_P   = T2;                 // 1048576 = NCHUNK*32768
  float* SC_S   = CAT;                // 1048576
  float* SC_HIN = T2;                 // aliases P (scan_mid reads before write)

  embed_kernel<<<2048, 256, 0, stream>>>(tgt, emb, X);

  for (int i = 0; i < NLAYERS; ++i) {
    // ---------- self mamba (L = 512, CL = 16) ----------
    mgemm<0, false><<<dim3(32, 16), 256, 0, stream>>>(
        X, in_w_s + (size_t)i * 1048576, nullptr, XZ, 1024, 2048, 512, 512);
    conv_silu_kernel<<<4096, 256, 0, stream>>>(
        XZ, conv_w_s + (size_t)i * 4096, conv_b_s + (size_t)i * 1024, XC, 512);
    mgemm<0, true><<<dim3(1, 16, 8), 256, 0, stream>>>(
        XC, xproj_s + (size_t)i * 65536, nullptr, DT /*partials*/, 1024, 64, 1024, 1024);
    reduce_epi_kernel<0><<<256, 256, 0, stream>>>(DT, nullptr, DBL, 65536, 8, 0);
    mgemm<3, false><<<dim3(16, 16), 256, 0, stream>>>(
        DBL, dtw_s + (size_t)i * 32768, dtb_s + (size_t)i * 1024, DT, 1024, 1024, 32, 64);
    scan_pass1<<<dim3(4, 2, NCHUNK), 256, 0, stream>>>(
        DT, DBL, XC, Alog_s + (size_t)i * 16384, SC_P, SC_S, 512, 512 / NCHUNK);
    scan_mid<<<128, 256, 0, stream>>>(SC_P, SC_S, SC_HIN, NCHUNK);
    scan_pass2<<<dim3(4, 2, NCHUNK), 256, 0, stream>>>(
        DT, DBL, XC, XZ, Alog_s + (size_t)i * 16384, D_s + (size_t)i * 1024,
        SC_HIN, YS, 512, 512 / NCHUNK);
    mgemm<0, true><<<dim3(8, 16, 4), 256, 0, stream>>>(
        YS, outw_s + (size_t)i * 524288, nullptr, XC /*partials*/, 1024, 512, 1024, 1024);
    reduce_epi_kernel<0><<<2048, 256, 0, stream>>>(XC, nullptr, T2, 524288, 4, 0);
    ln_kernel<<<1024, 64, 0, stream>>>(
        X, T2, (long long)512 * 512, 0, ln_g + (size_t)(i * 3 + 0) * 512,
        ln_b + (size_t)(i * 3 + 0) * 512, X);

    // ---------- cross mamba (L = 1024, CL = 32) ----------
    concat_kernel<<<1024, 256, 0, stream>>>(src, X, CAT);
    mgemm<0, false><<<dim3(32, 32), 256, 0, stream>>>(
        CAT, in_w_c + (size_t)i * 1048576, nullptr, XZ, 2048, 2048, 512, 512);
    conv_silu_kernel<<<8192, 256, 0, stream>>>(
        XZ, conv_w_c + (size_t)i * 4096, conv_b_c + (size_t)i * 1024, XC, 1024);
    mgemm<0, true><<<dim3(1, 32, 8), 256, 0, stream>>>(
        XC, xproj_c + (size_t)i * 65536, nullptr, DT /*partials*/, 2048, 64, 1024, 1024);
    reduce_epi_kernel<0><<<512, 256, 0, stream>>>(DT, nullptr, DBL, 131072, 8, 0);
    mgemm<3, false><<<dim3(16, 32), 256, 0, stream>>>(
        DBL, dtw_c + (size_t)i * 32768, dtb_c + (size_t)i * 1024, DT, 2048, 1024, 32, 64);
    scan_pass1<<<dim3(4, 2, NCHUNK), 256, 0, stream>>>(
        DT, DBL, XC, Alog_c + (size_t)i * 16384, SC_P, SC_S, 1024, 1024 / NCHUNK);
    scan_mid<<<128, 256, 0, stream>>>(SC_P, SC_S, SC_HIN, NCHUNK);
    scan_pass2<<<dim3(4, 2, NCHUNK), 256, 0, stream>>>(
        DT, DBL, XC, XZ, Alog_c + (size_t)i * 16384, D_c + (size_t)i * 1024,
        SC_HIN, YS, 1024, 1024 / NCHUNK);
    mgemm<0, true><<<dim3(8, 32, 4), 256, 0, stream>>>(
        YS, outw_c + (size_t)i * 524288, nullptr, XC /*partials*/, 2048, 512, 1024, 1024);
    reduce_epi_kernel<0><<<4096, 256, 0, stream>>>(XC, nullptr, T2, 1048576, 4, 0);
    ln_kernel<<<1024, 64, 0, stream>>>(
        X, T2, (long long)1024 * 512, (long long)512 * 512,
        ln_g + (size_t)(i * 3 + 1) * 512, ln_b + (size_t)(i * 3 + 1) * 512, X);

    // ---------- FFN ----------
    mgemm<1, false><<<dim3(32, 16), 256, 0, stream>>>(
        X, ffn_w1 + (size_t)i * 1048576, ffn_b1 + (size_t)i * 2048, XZ, 1024, 2048, 512, 512);
    mgemm<0, true><<<dim3(8, 16, 8), 256, 0, stream>>>(
        XZ, ffn_w2 + (size_t)i * 1048576, nullptr, XC /*partials*/, 1024, 512, 2048, 2048);
    reduce_epi_kernel<2><<<2048, 256, 0, stream>>>(
        XC, ffn_b2 + (size_t)i * 512, T2, 524288, 8, 511);
    ln_kernel<<<1024, 64, 0, stream>>>(
        X, T2, (long long)512 * 512, 0, ln_g + (size_t)(i * 3 + 2) * 512,
        ln_b + (size_t)(i * 3 + 2) * 512, X);
  }

  ln_kernel<<<1024, 64, 0, stream>>>(
      X, nullptr, 0, 0, fin_g, fin_b, (float*)d_out);
}

// Round 6
// 1222.978 us; speedup vs baseline: 5.2440x; 1.2072x over previous
//
#include <hip/hip_runtime.h>
#include <math.h>

#define DMODEL 512
#define DINNER 1024
#define DSTATE 16
#define DTRANK 32
#define NLAYERS 6
#define BB 2
#define LT 512
#define LS 512
#define NCHUNK 32

typedef __attribute__((ext_vector_type(8))) short bf16x8;
typedef __attribute__((ext_vector_type(8))) unsigned short u16x8;
typedef __attribute__((ext_vector_type(4))) float f32x4;

// fp32 -> bf16 round-to-nearest-even
__device__ __forceinline__ unsigned short f2bf(float f) {
  unsigned u = __float_as_uint(f);
  u += 0x7fffu + ((u >> 16) & 1u);
  return (unsigned short)(u >> 16);
}

// 0=none, 1=bias+relu, 2=bias, 3=bias+softplus
template<int EPI>
__device__ __forceinline__ float epi_apply(float acc, float b) {
  if (EPI == 1) { float v = acc + b; return v > 0.f ? v : 0.f; }
  if (EPI == 2) { return acc + b; }
  if (EPI == 3) { float v = acc + b; return fmaxf(v, 0.f) + log1pf(__expf(-fabsf(v))); }
  return acc;
}

// ---------------- fp32 -> bf16 bulk convert (weights) ----------------
__global__ __launch_bounds__(256) void cvt_kernel(const float* __restrict__ in,
    unsigned short* __restrict__ out, int n8) {
  int i = blockIdx.x * 256 + threadIdx.x;
  if (i >= n8) return;
  float4 a = ((const float4*)in)[i * 2];
  float4 b = ((const float4*)in)[i * 2 + 1];
  u16x8 o;
  o[0] = f2bf(a.x); o[1] = f2bf(a.y); o[2] = f2bf(a.z); o[3] = f2bf(a.w);
  o[4] = f2bf(b.x); o[5] = f2bf(b.y); o[6] = f2bf(b.z); o[7] = f2bf(b.w);
  *(u16x8*)&out[i * 8] = o;
}

// ---------------- embedding + sinusoidal PE ----------------
__global__ __launch_bounds__(256) void embed_kernel(const int* __restrict__ tgt,
    const float* __restrict__ emb, float* __restrict__ X,
    unsigned short* __restrict__ Xb) {
  int i = blockIdx.x * 256 + threadIdx.x;
  int d = i & (DMODEL - 1);
  int bt = i >> 9;
  int t = bt & (LT - 1);
  int tok = tgt[bt];
  float div = __expf((float)(d & ~1) * (-9.210340371976184f / (float)DMODEL));
  float ang = (float)t * div;
  float pe = (d & 1) ? cosf(ang) : sinf(ang);
  float v = emb[(size_t)tok * DMODEL + d] * 22.627416997969522f + pe;
  X[i] = v;
  Xb[i] = f2bf(v);
}

// ---------------- concat [src, x] -> bf16 ----------------
__global__ __launch_bounds__(256) void concat_kernel(const float* __restrict__ src,
    const float* __restrict__ X, unsigned short* __restrict__ CATb) {
  int i = blockIdx.x * 256 + threadIdx.x;   // 8 elems per thread over 2*1024*512
  int c8 = (i & 63) * 8;
  int r = i >> 6;
  int l = r & 1023;
  int b = r >> 10;
  const float* s = (l < LS) ? (src + ((size_t)b * LS + l) * DMODEL)
                            : (X + ((size_t)b * LT + (l - LS)) * DMODEL);
  float4 a = *(const float4*)(s + c8);
  float4 bq = *(const float4*)(s + c8 + 4);
  u16x8 o;
  o[0] = f2bf(a.x); o[1] = f2bf(a.y); o[2] = f2bf(a.z); o[3] = f2bf(a.w);
  o[4] = f2bf(bq.x); o[5] = f2bf(bq.y); o[6] = f2bf(bq.z); o[7] = f2bf(bq.w);
  *(u16x8*)&CATb[(size_t)r * DMODEL + c8] = o;
}

// ---------------- MFMA GEMM, bf16 operands: C[M,N] = A[M,K] * Bw[N,K]^T ----------
// 64x64 tile, 4 waves (2x2), 32x32 per wave (2x2 frags of 16x16x32).
// SPLIT: gridDim.z-way K-split, fp32 partials to C (+z*M*N), no epilogue.
// OUTB: write bf16 output to Cb instead of fp32 C.
template<int BK, int EPI, bool SPLIT, bool OUTB>
__global__ __launch_bounds__(256) void mgemm(
    const unsigned short* __restrict__ A, const unsigned short* __restrict__ Bw,
    const float* __restrict__ bias, float* __restrict__ C,
    unsigned short* __restrict__ Cb, int M, int N, int K, int lda) {
  constexpr int PAD = BK + 8;
  constexpr int CH = BK / 32;         // 16B chunks per thread per operand
  __shared__ __align__(16) unsigned short As[64 * PAD];
  __shared__ __align__(16) unsigned short Bs[64 * PAD];
  const int tid = threadIdx.x;
  const int bn = blockIdx.x * 64;
  const int bm = blockIdx.y * 64;
  const int lane = tid & 63;
  const int w = tid >> 6;
  const int wr = (w >> 1) * 32;
  const int wc = (w & 1) * 32;
  const int l15 = lane & 15;
  const int l4 = lane >> 4;
  const int koff = l4 * 8;
  int kcnt = K, kbeg = 0;
  if (SPLIT) { kcnt = K / (int)gridDim.z; kbeg = blockIdx.z * kcnt; }
  const int nt = kcnt / BK;
  f32x4 acc[2][2] = {};

  int row_[CH], k8_[CH];
  const unsigned short *Ap[CH], *Bp[CH];
#pragma unroll
  for (int i = 0; i < CH; ++i) {
    int f = tid + 256 * i;
    row_[i] = f / (BK / 8);
    k8_[i] = (f % (BK / 8)) * 8;
    Ap[i] = A + (size_t)(bm + row_[i]) * lda + kbeg + k8_[i];
    Bp[i] = Bw + (size_t)(bn + row_[i]) * K + kbeg + k8_[i];
  }

  u16x8 av[CH], bv[CH];
#pragma unroll
  for (int i = 0; i < CH; ++i) { av[i] = *(const u16x8*)Ap[i]; bv[i] = *(const u16x8*)Bp[i]; }

  for (int t = 0; t < nt; ++t) {
    __syncthreads();
#pragma unroll
    for (int i = 0; i < CH; ++i) {
      *(u16x8*)&As[row_[i] * PAD + k8_[i]] = av[i];
      *(u16x8*)&Bs[row_[i] * PAD + k8_[i]] = bv[i];
    }
    if (t + 1 < nt) {
      int ko = (t + 1) * BK;
#pragma unroll
      for (int i = 0; i < CH; ++i) {
        av[i] = *(const u16x8*)(Ap[i] + ko);
        bv[i] = *(const u16x8*)(Bp[i] + ko);
      }
    }
    __syncthreads();
#pragma unroll
    for (int kk = 0; kk < CH; ++kk) {
      bf16x8 afr[2], bfr[2];
#pragma unroll
      for (int i = 0; i < 2; ++i) {
        afr[i] = *(const bf16x8*)&As[(wr + i * 16 + l15) * PAD + kk * 32 + koff];
        bfr[i] = *(const bf16x8*)&Bs[(wc + i * 16 + l15) * PAD + kk * 32 + koff];
      }
#pragma unroll
      for (int fr = 0; fr < 2; ++fr)
#pragma unroll
        for (int fc = 0; fc < 2; ++fc)
          acc[fr][fc] = __builtin_amdgcn_mfma_f32_16x16x32_bf16(
              afr[fr], bfr[fc], acc[fr][fc], 0, 0, 0);
    }
  }

  if (SPLIT) {
    float* Pz = C + (size_t)blockIdx.z * M * N;
#pragma unroll
    for (int fc = 0; fc < 2; ++fc) {
      int col = bn + wc + fc * 16 + l15;
#pragma unroll
      for (int fr = 0; fr < 2; ++fr) {
        int row0 = bm + wr + fr * 16 + l4 * 4;
#pragma unroll
        for (int r = 0; r < 4; ++r)
          Pz[(size_t)(row0 + r) * N + col] = acc[fr][fc][r];
      }
    }
  } else {
#pragma unroll
    for (int fc = 0; fc < 2; ++fc) {
      int col = bn + wc + fc * 16 + l15;
      float bvs = (EPI != 0) ? bias[col] : 0.f;
#pragma unroll
      for (int fr = 0; fr < 2; ++fr) {
        int row0 = bm + wr + fr * 16 + l4 * 4;
#pragma unroll
        for (int r = 0; r < 4; ++r) {
          float v = epi_apply<EPI>(acc[fr][fc][r], bvs);
          if (OUTB) Cb[(size_t)(row0 + r) * N + col] = f2bf(v);
          else      C[(size_t)(row0 + r) * N + col] = v;
        }
      }
    }
  }
}

// ---------------- xproj split-K reduce -> DBL fp32 + DBLb bf16 (cols 0..31) ----
__global__ __launch_bounds__(256) void xred_kernel(const float* __restrict__ P,
    float* __restrict__ DBL, unsigned short* __restrict__ DBLb, int total) {
  int i = blockIdx.x * 256 + threadIdx.x;
  if (i >= total) return;
  float s = 0.f;
  for (int z = 0; z < 8; ++z) s += P[(size_t)z * total + i];
  DBL[i] = s;
  int col = i & 63;
  if (col < 32) DBLb[(size_t)(i >> 6) * 32 + col] = f2bf(s);
}

// ---------------- causal depthwise conv (k=4) + bias + silu ----------------
__global__ __launch_bounds__(256) void conv_silu_kernel(
    const float* __restrict__ xz, const float* __restrict__ w,
    const float* __restrict__ bias, float* __restrict__ out,
    unsigned short* __restrict__ outb, int L) {
  int idx = blockIdx.x * 256 + threadIdx.x;
  int d = idx & (DINNER - 1);
  int bt = idx >> 10;
  int b = bt / L;
  int t = bt - b * L;
  const float* col = xz + ((size_t)b * L) * (2 * DINNER) + d;
  float acc = bias[d];
#pragma unroll
  for (int k = 0; k < 4; ++k) {
    int tt = t - 3 + k;
    if (tt >= 0) acc = fmaf(col[(size_t)tt * (2 * DINNER)], w[d * 4 + k], acc);
  }
  float sig = 1.f / (1.f + __expf(-acc));
  float v = acc * sig;
  out[idx] = v;
  outb[idx] = f2bf(v);
}

// ---------------- chunked selective scan, lane = one (b,d) channel ----------------
__global__ __launch_bounds__(256) void scan_pass1(
    const float* __restrict__ dt, const float* __restrict__ dbl,
    const float* __restrict__ u, const float* __restrict__ Alog,
    float* __restrict__ P, float* __restrict__ S, int L, int CL) {
  __shared__ float BC[32][32];
  const int tid = threadIdx.x;
  const int d = blockIdx.x * 256 + tid;
  const int b = blockIdx.y;
  const int c = blockIdx.z;
  const int t0 = c * CL;
  if (tid < CL * 8) {
    int t = tid >> 3, j4 = (tid & 7) * 4;
    *(float4*)&BC[t][j4] = *(const float4*)(dbl + ((size_t)b * L + t0 + t) * 64 + 32 + j4);
  }
  float A[16], h[16], Pp[16];
#pragma unroll
  for (int j = 0; j < 4; ++j) {
    float4 a4 = *(const float4*)(Alog + d * 16 + j * 4);
    A[j * 4 + 0] = -__expf(a4.x); A[j * 4 + 1] = -__expf(a4.y);
    A[j * 4 + 2] = -__expf(a4.z); A[j * 4 + 3] = -__expf(a4.w);
  }
#pragma unroll
  for (int n = 0; n < 16; ++n) { h[n] = 0.f; Pp[n] = 1.f; }
  const float* dtp = dt + ((size_t)b * L + t0) * DINNER + d;
  const float* up  = u  + ((size_t)b * L + t0) * DINNER + d;
  __syncthreads();
  float dtv = dtp[0], uv = up[0];
  for (int t = 0; t < CL; ++t) {
    float dtn = 0.f, un = 0.f;
    if (t + 1 < CL) { dtn = dtp[(size_t)(t + 1) * DINNER]; un = up[(size_t)(t + 1) * DINNER]; }
    float du = dtv * uv;
    float Bv[16];
#pragma unroll
    for (int j = 0; j < 4; ++j) {
      float4 b4 = *(const float4*)&BC[t][j * 4];
      Bv[j * 4 + 0] = b4.x; Bv[j * 4 + 1] = b4.y; Bv[j * 4 + 2] = b4.z; Bv[j * 4 + 3] = b4.w;
    }
#pragma unroll
    for (int n = 0; n < 16; ++n) {
      float dA = __expf(dtv * A[n]);
      Pp[n] *= dA;
      h[n] = fmaf(dA, h[n], du * Bv[n]);
    }
    dtv = dtn; uv = un;
  }
  size_t base = (size_t)c * 32768 + ((size_t)(b * 1024 + d) << 4);
#pragma unroll
  for (int j = 0; j < 4; ++j) {
    *(float4*)&P[base + j * 4] = make_float4(Pp[j*4], Pp[j*4+1], Pp[j*4+2], Pp[j*4+3]);
    *(float4*)&S[base + j * 4] = make_float4(h[j*4], h[j*4+1], h[j*4+2], h[j*4+3]);
  }
}

__global__ __launch_bounds__(256) void scan_mid(
    const float* __restrict__ P, const float* __restrict__ S,
    float* __restrict__ HIN, int C) {
  int s = blockIdx.x * 256 + threadIdx.x;
  float h = 0.f;
  for (int c = 0; c < C; ++c) {
    float p = P[(size_t)c * 32768 + s];
    float sv = S[(size_t)c * 32768 + s];
    HIN[(size_t)c * 32768 + s] = h;
    h = fmaf(p, h, sv);
  }
}

// pass2: chunks c0.., writes compact bf16 y (rows b*512 + t0 - c0*CL + t)
__global__ __launch_bounds__(256) void scan_pass2(
    const float* __restrict__ dt, const float* __restrict__ dbl,
    const float* __restrict__ u, const float* __restrict__ xz,
    const float* __restrict__ Alog, const float* __restrict__ Dsk,
    const float* __restrict__ HIN, unsigned short* __restrict__ ysb,
    int L, int CL, int c0) {
  __shared__ float BC[32][32];
  const int tid = threadIdx.x;
  const int d = blockIdx.x * 256 + tid;
  const int b = blockIdx.y;
  const int c = blockIdx.z + c0;
  const int t0 = c * CL;
  if (tid < CL * 8) {
    int t = tid >> 3, j4 = (tid & 7) * 4;
    *(float4*)&BC[t][j4] = *(const float4*)(dbl + ((size_t)b * L + t0 + t) * 64 + 32 + j4);
  }
  float A[16], h[16];
#pragma unroll
  for (int j = 0; j < 4; ++j) {
    float4 a4 = *(const float4*)(Alog + d * 16 + j * 4);
    A[j * 4 + 0] = -__expf(a4.x); A[j * 4 + 1] = -__expf(a4.y);
    A[j * 4 + 2] = -__expf(a4.z); A[j * 4 + 3] = -__expf(a4.w);
  }
  size_t base = (size_t)c * 32768 + ((size_t)(b * 1024 + d) << 4);
#pragma unroll
  for (int j = 0; j < 4; ++j) {
    float4 h4 = *(const float4*)&HIN[base + j * 4];
    h[j * 4 + 0] = h4.x; h[j * 4 + 1] = h4.y; h[j * 4 + 2] = h4.z; h[j * 4 + 3] = h4.w;
  }
  float Dv = Dsk[d];
  const float* dtp = dt + ((size_t)b * L + t0) * DINNER + d;
  const float* up  = u  + ((size_t)b * L + t0) * DINNER + d;
  const float* zp  = xz + ((size_t)b * L + t0) * (2 * DINNER) + DINNER + d;
  unsigned short* yp = ysb + ((size_t)(b * 512) + (t0 - c0 * CL)) * DINNER + d;
  __syncthreads();
  float dtv = dtp[0], uv = up[0], zv = zp[0];
  for (int t = 0; t < CL; ++t) {
    float dtn = 0.f, un = 0.f, zn = 0.f;
    if (t + 1 < CL) {
      dtn = dtp[(size_t)(t + 1) * DINNER];
      un  = up[(size_t)(t + 1) * DINNER];
      zn  = zp[(size_t)(t + 1) * (2 * DINNER)];
    }
    float du = dtv * uv;
    float Bv[16], Cv[16];
#pragma unroll
    for (int j = 0; j < 4; ++j) {
      float4 b4 = *(const float4*)&BC[t][j * 4];
      float4 c4 = *(const float4*)&BC[t][16 + j * 4];
      Bv[j*4+0] = b4.x; Bv[j*4+1] = b4.y; Bv[j*4+2] = b4.z; Bv[j*4+3] = b4.w;
      Cv[j*4+0] = c4.x; Cv[j*4+1] = c4.y; Cv[j*4+2] = c4.z; Cv[j*4+3] = c4.w;
    }
    float y = 0.f;
#pragma unroll
    for (int n = 0; n < 16; ++n) {
      float dA = __expf(dtv * A[n]);
      h[n] = fmaf(dA, h[n], du * Bv[n]);
      y = fmaf(h[n], Cv[n], y);
    }
    float sig = 1.f / (1.f + __expf(-zv));
    yp[(size_t)t * DINNER] = f2bf((y + uv * Dv) * (zv * sig));
    dtv = dtn; uv = un; zv = zn;
  }
}

// ---------------- fused split-K reduce + residual + LayerNorm ----------------
// out = LN(res + epi(sum_z P, bias)); also writes bf16 mirror.
template<int NZ, int EPI>
__global__ __launch_bounds__(64) void ln_red_kernel(
    const float* __restrict__ res, const float* __restrict__ P,
    const float* __restrict__ bias, const float* __restrict__ g,
    const float* __restrict__ be, float* __restrict__ out,
    unsigned short* __restrict__ outb) {
  int r = blockIdx.x;
  int lane = threadIdx.x;
  const float* rp = res + (size_t)r * DMODEL;
  float v[8];
  float s = 0.f, ss = 0.f;
#pragma unroll
  for (int j = 0; j < 8; ++j) {
    int col = lane + j * 64;
    float acc = 0.f;
#pragma unroll
    for (int z = 0; z < NZ; ++z) acc += P[(size_t)z * 524288 + (size_t)r * DMODEL + col];
    float bv = (EPI != 0) ? bias[col] : 0.f;
    float x = rp[col] + epi_apply<EPI>(acc, bv);
    v[j] = x; s += x; ss += x * x;
  }
#pragma unroll
  for (int o = 32; o > 0; o >>= 1) { s += __shfl_xor(s, o); ss += __shfl_xor(ss, o); }
  float m = s * (1.f / 512.f);
  float var = ss * (1.f / 512.f) - m * m;
  float rs = rsqrtf(var + 1e-6f);
#pragma unroll
  for (int j = 0; j < 8; ++j) {
    int col = lane + j * 64;
    float o2 = (v[j] - m) * rs * g[col] + be[col];
    out[(size_t)r * DMODEL + col] = o2;
    outb[(size_t)r * DMODEL + col] = f2bf(o2);
  }
}

// ---------------- final LayerNorm ----------------
__global__ __launch_bounds__(64) void ln_final_kernel(
    const float* __restrict__ res, const float* __restrict__ g,
    const float* __restrict__ be, float* __restrict__ out) {
  int r = blockIdx.x;
  int lane = threadIdx.x;
  const float* rp = res + (size_t)r * DMODEL;
  float v[8];
  float s = 0.f, ss = 0.f;
#pragma unroll
  for (int j = 0; j < 8; ++j) {
    float x = rp[lane + j * 64];
    v[j] = x; s += x; ss += x * x;
  }
#pragma unroll
  for (int o = 32; o > 0; o >>= 1) { s += __shfl_xor(s, o); ss += __shfl_xor(ss, o); }
  float m = s * (1.f / 512.f);
  float var = ss * (1.f / 512.f) - m * m;
  float rs = rsqrtf(var + 1e-6f);
#pragma unroll
  for (int j = 0; j < 8; ++j) {
    int c = lane + j * 64;
    out[(size_t)r * DMODEL + c] = (v[j] - m) * rs * g[c] + be[c];
  }
}

// ---------------- orchestration ----------------
extern "C" void kernel_launch(void* const* d_in, const int* in_sizes, int n_in,
                              void* d_out, int out_size, void* d_ws, size_t ws_size,
                              hipStream_t stream) {
  (void)in_sizes; (void)n_in; (void)out_size; (void)ws_size;
  const float* src      = (const float*)d_in[0];
  const int*   tgt      = (const int*)d_in[1];
  const float* emb      = (const float*)d_in[2];
  const float* in_w_s   = (const float*)d_in[3];
  const float* conv_w_s = (const float*)d_in[4];
  const float* conv_b_s = (const float*)d_in[5];
  const float* xproj_s  = (const float*)d_in[6];
  const float* dtw_s    = (const float*)d_in[7];
  const float* dtb_s    = (const float*)d_in[8];
  const float* Alog_s   = (const float*)d_in[9];
  const float* D_s      = (const float*)d_in[10];
  const float* outw_s   = (const float*)d_in[11];
  const float* in_w_c   = (const float*)d_in[12];
  const float* conv_w_c = (const float*)d_in[13];
  const float* conv_b_c = (const float*)d_in[14];
  const float* xproj_c  = (const float*)d_in[15];
  const float* dtw_c    = (const float*)d_in[16];
  const float* dtb_c    = (const float*)d_in[17];
  const float* Alog_c   = (const float*)d_in[18];
  const float* D_c      = (const float*)d_in[19];
  const float* outw_c   = (const float*)d_in[20];
  const float* ffn_w1   = (const float*)d_in[21];
  const float* ffn_b1   = (const float*)d_in[22];
  const float* ffn_w2   = (const float*)d_in[23];
  const float* ffn_b2   = (const float*)d_in[24];
  const float* ln_g     = (const float*)d_in[25];
  const float* ln_b     = (const float*)d_in[26];
  const float* fin_g    = (const float*)d_in[27];
  const float* fin_b    = (const float*)d_in[28];

  // ---- workspace layout (ws_size ~268 MB; we use ~124 MB) ----
  float* ws   = (float*)d_ws;
  float* X    = ws;                   // 524288
  float* XZ   = X + 524288;           // 4194304  (in_proj out; split-K partials later)
  float* XC   = XZ + 4194304;         // 2097152
  float* DT   = XC + 2097152;         // 2097152
  float* DBL  = DT + 2097152;         // 131072
  float* SC_P = DBL + 131072;         // 1048576  (xproj partials / scan P / HIN)
  float* SC_S = SC_P + 1048576;       // 1048576
  unsigned short* U = (unsigned short*)(SC_S + 1048576);
  unsigned short* Xb   = U;                   // 524288 u
  unsigned short* CATb = Xb + 524288;         // 1048576 u
  unsigned short* XCb  = CATb + 1048576;      // 2097152 u
  unsigned short* DBLb = XCb + 2097152;       // 65536 u (2048x32)
  unsigned short* XZb  = DBLb + 65536;        // 2097152 u (ffn hidden)
  unsigned short* YSb  = XZb + 2097152;       // 1048576 u (2,512,1024)
  unsigned short* WB   = YSb + 1048576;
  unsigned short* inwsb = WB;
  unsigned short* inwcb = inwsb + 6291456;
  unsigned short* xpsb  = inwcb + 6291456;
  unsigned short* xpcb  = xpsb + 393216;
  unsigned short* dtwsb = xpcb + 393216;
  unsigned short* dtwcb = dtwsb + 196608;
  unsigned short* owsb  = dtwcb + 196608;
  unsigned short* owcb  = owsb + 3145728;
  unsigned short* f1b   = owcb + 3145728;
  unsigned short* f2b   = f1b + 6291456;

  // ---- weight conversion (once per call) ----
  cvt_kernel<<<3072, 256, 0, stream>>>(in_w_s, inwsb, 786432);
  cvt_kernel<<<3072, 256, 0, stream>>>(in_w_c, inwcb, 786432);
  cvt_kernel<<<192, 256, 0, stream>>>(xproj_s, xpsb, 49152);
  cvt_kernel<<<192, 256, 0, stream>>>(xproj_c, xpcb, 49152);
  cvt_kernel<<<96, 256, 0, stream>>>(dtw_s, dtwsb, 24576);
  cvt_kernel<<<96, 256, 0, stream>>>(dtw_c, dtwcb, 24576);
  cvt_kernel<<<1536, 256, 0, stream>>>(outw_s, owsb, 393216);
  cvt_kernel<<<1536, 256, 0, stream>>>(outw_c, owcb, 393216);
  cvt_kernel<<<3072, 256, 0, stream>>>(ffn_w1, f1b, 786432);
  cvt_kernel<<<3072, 256, 0, stream>>>(ffn_w2, f2b, 786432);

  embed_kernel<<<2048, 256, 0, stream>>>(tgt, emb, X, Xb);

  for (int i = 0; i < NLAYERS; ++i) {
    // ---------- self mamba (L = 512, CL = 16) ----------
    mgemm<64, 0, false, false><<<dim3(32, 16), 256, 0, stream>>>(
        Xb, inwsb + (size_t)i * 1048576, nullptr, XZ, nullptr, 1024, 2048, 512, 512);
    conv_silu_kernel<<<4096, 256, 0, stream>>>(
        XZ, conv_w_s + (size_t)i * 4096, conv_b_s + (size_t)i * 1024, XC, XCb, 512);
    mgemm<64, 0, true, false><<<dim3(1, 16, 8), 256, 0, stream>>>(
        XCb, xpsb + (size_t)i * 65536, nullptr, SC_P, nullptr, 1024, 64, 1024, 1024);
    xred_kernel<<<256, 256, 0, stream>>>(SC_P, DBL, DBLb, 65536);
    mgemm<32, 3, false, false><<<dim3(16, 16), 256, 0, stream>>>(
        DBLb, dtwsb + (size_t)i * 32768, dtb_s + (size_t)i * 1024, DT, nullptr,
        1024, 1024, 32, 32);
    scan_pass1<<<dim3(4, 2, 32), 256, 0, stream>>>(
        DT, DBL, XC, Alog_s + (size_t)i * 16384, SC_P, SC_S, 512, 16);
    scan_mid<<<128, 256, 0, stream>>>(SC_P, SC_S, SC_P, 32);
    scan_pass2<<<dim3(4, 2, 32), 256, 0, stream>>>(
        DT, DBL, XC, XZ, Alog_s + (size_t)i * 16384, D_s + (size_t)i * 1024,
        SC_P, YSb, 512, 16, 0);
    mgemm<64, 0, true, false><<<dim3(8, 16, 4), 256, 0, stream>>>(
        YSb, owsb + (size_t)i * 524288, nullptr, XZ, nullptr, 1024, 512, 1024, 1024);
    ln_red_kernel<4, 0><<<1024, 64, 0, stream>>>(
        X, XZ, nullptr, ln_g + (size_t)(i * 3 + 0) * 512,
        ln_b + (size_t)(i * 3 + 0) * 512, X, Xb);

    // ---------- cross mamba (L = 1024, CL = 32; only last 512 t produce y) ----------
    concat_kernel<<<512, 256, 0, stream>>>(src, X, CATb);
    mgemm<64, 0, false, false><<<dim3(32, 32), 256, 0, stream>>>(
        CATb, inwcb + (size_t)i * 1048576, nullptr, XZ, nullptr, 2048, 2048, 512, 512);
    conv_silu_kernel<<<8192, 256, 0, stream>>>(
        XZ, conv_w_c + (size_t)i * 4096, conv_b_c + (size_t)i * 1024, XC, XCb, 1024);
    mgemm<64, 0, true, false><<<dim3(1, 32, 8), 256, 0, stream>>>(
        XCb, xpcb + (size_t)i * 65536, nullptr, SC_P, nullptr, 2048, 64, 1024, 1024);
    xred_kernel<<<512, 256, 0, stream>>>(SC_P, DBL, DBLb, 131072);
    mgemm<32, 3, false, false><<<dim3(16, 32), 256, 0, stream>>>(
        DBLb, dtwcb + (size_t)i * 32768, dtb_c + (size_t)i * 1024, DT, nullptr,
        2048, 1024, 32, 32);
    scan_pass1<<<dim3(4, 2, 32), 256, 0, stream>>>(
        DT, DBL, XC, Alog_c + (size_t)i * 16384, SC_P, SC_S, 1024, 32);
    scan_mid<<<128, 256, 0, stream>>>(SC_P, SC_S, SC_P, 32);
    scan_pass2<<<dim3(4, 2, 16), 256, 0, stream>>>(
        DT, DBL, XC, XZ, Alog_c + (size_t)i * 16384, D_c + (size_t)i * 1024,
        SC_P, YSb, 1024, 32, 16);
    mgemm<64, 0, true, false><<<dim3(8, 16, 4), 256, 0, stream>>>(
        YSb, owcb + (size_t)i * 524288, nullptr, XZ, nullptr, 1024, 512, 1024, 1024);
    ln_red_kernel<4, 0><<<1024, 64, 0, stream>>>(
        X, XZ, nullptr, ln_g + (size_t)(i * 3 + 1) * 512,
        ln_b + (size_t)(i * 3 + 1) * 512, X, Xb);

    // ---------- FFN ----------
    mgemm<64, 1, false, true><<<dim3(32, 16), 256, 0, stream>>>(
        Xb, f1b + (size_t)i * 1048576, ffn_b1 + (size_t)i * 2048, nullptr, XZb,
        1024, 2048, 512, 512);
    mgemm<64, 0, true, false><<<dim3(8, 16, 8), 256, 0, stream>>>(
        XZb, f2b + (size_t)i * 1048576, nullptr, XZ, nullptr, 1024, 512, 2048, 2048);
    ln_red_kernel<8, 2><<<1024, 64, 0, stream>>>(
        X, XZ, ffn_b2 + (size_t)i * 512, ln_g + (size_t)(i * 3 + 2) * 512,
        ln_b + (size_t)(i * 3 + 2) * 512, X, Xb);
  }

  ln_final_kernel<<<1024, 64, 0, stream>>>(X, fin_g, fin_b, (float*)d_out);
}

// Round 8
// 1193.784 us; speedup vs baseline: 5.3722x; 1.0245x over previous
//
#include <hip/hip_runtime.h>
#include <math.h>

#define DMODEL 512
#define DINNER 1024
#define DSTATE 16
#define DTRANK 32
#define NLAYERS 6
#define BB 2
#define LT 512
#define LS 512

typedef __attribute__((ext_vector_type(8))) short bf16x8;
typedef __attribute__((ext_vector_type(8))) unsigned short u16x8;
typedef __attribute__((ext_vector_type(4))) float f32x4;

__device__ __forceinline__ unsigned short f2bf(float f) {
  unsigned u = __float_as_uint(f);
  u += 0x7fffu + ((u >> 16) & 1u);
  return (unsigned short)(u >> 16);
}
__device__ __forceinline__ float bf2f(unsigned short u) {
  return __uint_as_float((unsigned)u << 16);
}

// 0=none, 1=bias+relu, 2=bias, 3=bias+softplus
template<int EPI>
__device__ __forceinline__ float epi_apply(float acc, float b) {
  if (EPI == 1) { float v = acc + b; return v > 0.f ? v : 0.f; }
  if (EPI == 2) { return acc + b; }
  if (EPI == 3) { float v = acc + b; return fmaxf(v, 0.f) + log1pf(__expf(-fabsf(v))); }
  return acc;
}

// ---------------- fused weight conversion (all 10 weight tensors) ----------------
// u16x8-unit cumulative offsets:
//   i0 in_w_s  [0,        786432)
//   i1 in_w_c  [786432,  1572864)
//   i2 xproj_s [1572864, 1622016)
//   i3 xproj_c [1622016, 1671168)
//   i4 dtw_s   [1671168, 1695744)
//   i5 dtw_c   [1695744, 1720320)
//   i6 outw_s  [1720320, 2113536)
//   i7 outw_c  [2113536, 2506752)
//   i8 ffn_w1  [2506752, 3293184)
//   i9 ffn_w2  [3293184, 4079616)
__global__ __launch_bounds__(256) void cvt_all_kernel(
    const float* __restrict__ i0, const float* __restrict__ i1,
    const float* __restrict__ i2, const float* __restrict__ i3,
    const float* __restrict__ i4, const float* __restrict__ i5,
    const float* __restrict__ i6, const float* __restrict__ i7,
    const float* __restrict__ i8, const float* __restrict__ i9,
    unsigned short* __restrict__ outbase) {
  int i = blockIdx.x * 256 + threadIdx.x;
  if (i >= 4079616) return;
  const float* in; int off;
  if      (i <  786432) { in = i0; off = i; }
  else if (i < 1572864) { in = i1; off = i -  786432; }
  else if (i < 1622016) { in = i2; off = i - 1572864; }
  else if (i < 1671168) { in = i3; off = i - 1622016; }
  else if (i < 1695744) { in = i4; off = i - 1671168; }
  else if (i < 1720320) { in = i5; off = i - 1695744; }
  else if (i < 2113536) { in = i6; off = i - 1720320; }
  else if (i < 2506752) { in = i7; off = i - 2113536; }
  else if (i < 3293184) { in = i8; off = i - 2506752; }
  else                  { in = i9; off = i - 3293184; }
  float4 a = ((const float4*)in)[off * 2];
  float4 b = ((const float4*)in)[off * 2 + 1];
  u16x8 o;
  o[0] = f2bf(a.x); o[1] = f2bf(a.y); o[2] = f2bf(a.z); o[3] = f2bf(a.w);
  o[4] = f2bf(b.x); o[5] = f2bf(b.y); o[6] = f2bf(b.z); o[7] = f2bf(b.w);
  *(u16x8*)&outbase[(size_t)i * 8] = o;
}

// ---------------- embedding + sinusoidal PE ----------------
__global__ __launch_bounds__(256) void embed_kernel(const int* __restrict__ tgt,
    const float* __restrict__ emb, float* __restrict__ X,
    unsigned short* __restrict__ Xb) {
  int i = blockIdx.x * 256 + threadIdx.x;
  int d = i & (DMODEL - 1);
  int bt = i >> 9;
  int t = bt & (LT - 1);
  int tok = tgt[bt];
  float div = __expf((float)(d & ~1) * (-9.210340371976184f / (float)DMODEL));
  float ang = (float)t * div;
  float pe = (d & 1) ? cosf(ang) : sinf(ang);
  float v = emb[(size_t)tok * DMODEL + d] * 22.627416997969522f + pe;
  X[i] = v;
  Xb[i] = f2bf(v);
}

// ---------------- one-time: src half of CATb (rows b*1024 + 0..511) ----------------
__global__ __launch_bounds__(256) void catsrc_kernel(const float* __restrict__ src,
    unsigned short* __restrict__ CATb) {
  int i = blockIdx.x * 256 + threadIdx.x;   // u16x8 units over 2*512*512
  int c8 = (i & 63) * 8;
  int r = i >> 6;                           // 0..1023
  int b = r >> 9, l = r & 511;
  const float* s = src + ((size_t)b * 512 + l) * DMODEL + c8;
  float4 a = *(const float4*)s;
  float4 bq = *(const float4*)(s + 4);
  u16x8 o;
  o[0] = f2bf(a.x); o[1] = f2bf(a.y); o[2] = f2bf(a.z); o[3] = f2bf(a.w);
  o[4] = f2bf(bq.x); o[5] = f2bf(bq.y); o[6] = f2bf(bq.z); o[7] = f2bf(bq.w);
  *(u16x8*)&CATb[((size_t)b * 1024 + l) * DMODEL + c8] = o;
}

// ---------------- MFMA GEMM 64x128 tile: C[M,N] = A[M,K] * Bw[N,K]^T ----------
// 4 waves (2x2), 32x64 per wave (2x4 frags of 16x16x32). bf16 in, fp32 acc.
template<int BK, int EPI, bool SPLIT, bool OUTB>
__global__ __launch_bounds__(256) void mgemmA(
    const unsigned short* __restrict__ A, const unsigned short* __restrict__ Bw,
    const float* __restrict__ bias, float* __restrict__ C,
    unsigned short* __restrict__ Cb, int M, int N, int K, int lda) {
  constexpr int PAD = BK + 8;
  constexpr int CHA = BK / 32;
  constexpr int CHB = BK / 16;
  __shared__ __align__(16) unsigned short As[64 * PAD];
  __shared__ __align__(16) unsigned short Bs[128 * PAD];
  const int tid = threadIdx.x;
  const int bn = blockIdx.x * 128;
  const int bm = blockIdx.y * 64;
  const int lane = tid & 63;
  const int w = tid >> 6;
  const int wr = (w >> 1) * 32;
  const int wc = (w & 1) * 64;
  const int l15 = lane & 15;
  const int l4 = lane >> 4;
  const int koff = l4 * 8;
  int kcnt = K, kbeg = 0;
  if (SPLIT) { kcnt = K / (int)gridDim.z; kbeg = blockIdx.z * kcnt; }
  const int nt = kcnt / BK;
  f32x4 acc[2][4] = {};

  int arow_[CHA], ak8_[CHA];
  const unsigned short* Ap[CHA];
#pragma unroll
  for (int i = 0; i < CHA; ++i) {
    int f = tid + 256 * i;
    arow_[i] = f / (BK / 8);
    ak8_[i] = (f % (BK / 8)) * 8;
    Ap[i] = A + (size_t)(bm + arow_[i]) * lda + kbeg + ak8_[i];
  }
  int brow_[CHB], bk8_[CHB];
  const unsigned short* Bp[CHB];
#pragma unroll
  for (int i = 0; i < CHB; ++i) {
    int f = tid + 256 * i;
    brow_[i] = f / (BK / 8);
    bk8_[i] = (f % (BK / 8)) * 8;
    Bp[i] = Bw + (size_t)(bn + brow_[i]) * K + kbeg + bk8_[i];
  }

  u16x8 av[CHA], bv[CHB];
#pragma unroll
  for (int i = 0; i < CHA; ++i) av[i] = *(const u16x8*)Ap[i];
#pragma unroll
  for (int i = 0; i < CHB; ++i) bv[i] = *(const u16x8*)Bp[i];

  for (int t = 0; t < nt; ++t) {
    __syncthreads();
#pragma unroll
    for (int i = 0; i < CHA; ++i) *(u16x8*)&As[arow_[i] * PAD + ak8_[i]] = av[i];
#pragma unroll
    for (int i = 0; i < CHB; ++i) *(u16x8*)&Bs[brow_[i] * PAD + bk8_[i]] = bv[i];
    if (t + 1 < nt) {
      int ko = (t + 1) * BK;
#pragma unroll
      for (int i = 0; i < CHA; ++i) av[i] = *(const u16x8*)(Ap[i] + ko);
#pragma unroll
      for (int i = 0; i < CHB; ++i) bv[i] = *(const u16x8*)(Bp[i] + ko);
    }
    __syncthreads();
#pragma unroll
    for (int kk = 0; kk < BK / 32; ++kk) {
      bf16x8 afr[2], bfr[4];
#pragma unroll
      for (int i = 0; i < 2; ++i)
        afr[i] = *(const bf16x8*)&As[(wr + i * 16 + l15) * PAD + kk * 32 + koff];
#pragma unroll
      for (int j = 0; j < 4; ++j)
        bfr[j] = *(const bf16x8*)&Bs[(wc + j * 16 + l15) * PAD + kk * 32 + koff];
#pragma unroll
      for (int fr = 0; fr < 2; ++fr)
#pragma unroll
        for (int fc = 0; fc < 4; ++fc)
          acc[fr][fc] = __builtin_amdgcn_mfma_f32_16x16x32_bf16(
              afr[fr], bfr[fc], acc[fr][fc], 0, 0, 0);
    }
  }

  if (SPLIT) {
    float* Pz = C + (size_t)blockIdx.z * M * N;
#pragma unroll
    for (int fc = 0; fc < 4; ++fc) {
      int col = bn + wc + fc * 16 + l15;
#pragma unroll
      for (int fr = 0; fr < 2; ++fr) {
        int row0 = bm + wr + fr * 16 + l4 * 4;
#pragma unroll
        for (int r = 0; r < 4; ++r)
          Pz[(size_t)(row0 + r) * N + col] = acc[fr][fc][r];
      }
    }
  } else {
#pragma unroll
    for (int fc = 0; fc < 4; ++fc) {
      int col = bn + wc + fc * 16 + l15;
      float bvs = (EPI != 0) ? bias[col] : 0.f;
#pragma unroll
      for (int fr = 0; fr < 2; ++fr) {
        int row0 = bm + wr + fr * 16 + l4 * 4;
#pragma unroll
        for (int r = 0; r < 4; ++r) {
          float v = epi_apply<EPI>(acc[fr][fc][r], bvs);
          if (OUTB) Cb[(size_t)(row0 + r) * N + col] = f2bf(v);
          else      C[(size_t)(row0 + r) * N + col] = v;
        }
      }
    }
  }
}

// ---------------- MFMA GEMM 64x64 tile (xproj N=64, dt K=32) ----------------
template<int BK, int EPI, bool SPLIT, bool OUTB>
__global__ __launch_bounds__(256) void mgemm(
    const unsigned short* __restrict__ A, const unsigned short* __restrict__ Bw,
    const float* __restrict__ bias, float* __restrict__ C,
    unsigned short* __restrict__ Cb, int M, int N, int K, int lda) {
  constexpr int PAD = BK + 8;
  constexpr int CH = BK / 32;
  __shared__ __align__(16) unsigned short As[64 * PAD];
  __shared__ __align__(16) unsigned short Bs[64 * PAD];
  const int tid = threadIdx.x;
  const int bn = blockIdx.x * 64;
  const int bm = blockIdx.y * 64;
  const int lane = tid & 63;
  const int w = tid >> 6;
  const int wr = (w >> 1) * 32;
  const int wc = (w & 1) * 32;
  const int l15 = lane & 15;
  const int l4 = lane >> 4;
  const int koff = l4 * 8;
  int kcnt = K, kbeg = 0;
  if (SPLIT) { kcnt = K / (int)gridDim.z; kbeg = blockIdx.z * kcnt; }
  const int nt = kcnt / BK;
  f32x4 acc[2][2] = {};

  int row_[CH], k8_[CH];
  const unsigned short *Ap[CH], *Bp[CH];
#pragma unroll
  for (int i = 0; i < CH; ++i) {
    int f = tid + 256 * i;
    row_[i] = f / (BK / 8);
    k8_[i] = (f % (BK / 8)) * 8;
    Ap[i] = A + (size_t)(bm + row_[i]) * lda + kbeg + k8_[i];
    Bp[i] = Bw + (size_t)(bn + row_[i]) * K + kbeg + k8_[i];
  }

  u16x8 av[CH], bv[CH];
#pragma unroll
  for (int i = 0; i < CH; ++i) { av[i] = *(const u16x8*)Ap[i]; bv[i] = *(const u16x8*)Bp[i]; }

  for (int t = 0; t < nt; ++t) {
    __syncthreads();
#pragma unroll
    for (int i = 0; i < CH; ++i) {
      *(u16x8*)&As[row_[i] * PAD + k8_[i]] = av[i];
      *(u16x8*)&Bs[row_[i] * PAD + k8_[i]] = bv[i];
    }
    if (t + 1 < nt) {
      int ko = (t + 1) * BK;
#pragma unroll
      for (int i = 0; i < CH; ++i) {
        av[i] = *(const u16x8*)(Ap[i] + ko);
        bv[i] = *(const u16x8*)(Bp[i] + ko);
      }
    }
    __syncthreads();
#pragma unroll
    for (int kk = 0; kk < CH; ++kk) {
      bf16x8 afr[2], bfr[2];
#pragma unroll
      for (int i = 0; i < 2; ++i) {
        afr[i] = *(const bf16x8*)&As[(wr + i * 16 + l15) * PAD + kk * 32 + koff];
        bfr[i] = *(const bf16x8*)&Bs[(wc + i * 16 + l15) * PAD + kk * 32 + koff];
      }
#pragma unroll
      for (int fr = 0; fr < 2; ++fr)
#pragma unroll
        for (int fc = 0; fc < 2; ++fc)
          acc[fr][fc] = __builtin_amdgcn_mfma_f32_16x16x32_bf16(
              afr[fr], bfr[fc], acc[fr][fc], 0, 0, 0);
    }
  }

  if (SPLIT) {
    float* Pz = C + (size_t)blockIdx.z * M * N;
#pragma unroll
    for (int fc = 0; fc < 2; ++fc) {
      int col = bn + wc + fc * 16 + l15;
#pragma unroll
      for (int fr = 0; fr < 2; ++fr) {
        int row0 = bm + wr + fr * 16 + l4 * 4;
#pragma unroll
        for (int r = 0; r < 4; ++r)
          Pz[(size_t)(row0 + r) * N + col] = acc[fr][fc][r];
      }
    }
  } else {
#pragma unroll
    for (int fc = 0; fc < 2; ++fc) {
      int col = bn + wc + fc * 16 + l15;
      float bvs = (EPI != 0) ? bias[col] : 0.f;
#pragma unroll
      for (int fr = 0; fr < 2; ++fr) {
        int row0 = bm + wr + fr * 16 + l4 * 4;
#pragma unroll
        for (int r = 0; r < 4; ++r) {
          float v = epi_apply<EPI>(acc[fr][fc][r], bvs);
          if (OUTB) Cb[(size_t)(row0 + r) * N + col] = f2bf(v);
          else      C[(size_t)(row0 + r) * N + col] = v;
        }
      }
    }
  }
}

// ---------------- xproj split-K reduce -> bf16 M x 64 ----------------
__global__ __launch_bounds__(256) void xred_kernel(const float* __restrict__ P,
    unsigned short* __restrict__ DBLb, int total) {
  int i = blockIdx.x * 256 + threadIdx.x;
  if (i >= total) return;
  float s = 0.f;
  for (int z = 0; z < 8; ++z) s += P[(size_t)z * total + i];
  DBLb[i] = f2bf(s);
}

// ---------------- causal depthwise conv (k=4) + bias + silu, bf16 io ----------------
__global__ __launch_bounds__(256) void conv_silu_kernel(
    const unsigned short* __restrict__ xzb, const float* __restrict__ w,
    const float* __restrict__ bias, unsigned short* __restrict__ outb, int L) {
  int idx = blockIdx.x * 256 + threadIdx.x;
  int d = idx & (DINNER - 1);
  int bt = idx >> 10;
  int b = bt / L;
  int t = bt - b * L;
  const unsigned short* col = xzb + ((size_t)b * L) * (2 * DINNER) + d;
  float acc = bias[d];
#pragma unroll
  for (int k = 0; k < 4; ++k) {
    int tt = t - 3 + k;
    if (tt >= 0) acc = fmaf(bf2f(col[(size_t)tt * (2 * DINNER)]), w[d * 4 + k], acc);
  }
  float sig = 1.f / (1.f + __expf(-acc));
  outb[idx] = f2bf(acc * sig);
}

// ---------------- chunked selective scan, lane = one (b,d) channel ----------------
// dt/u/BC in bf16; state fp32. grid (4, 2, nchunk).
__global__ __launch_bounds__(256) void scan_pass1(
    const unsigned short* __restrict__ dt, const unsigned short* __restrict__ dblb,
    const unsigned short* __restrict__ u, const float* __restrict__ Alog,
    float* __restrict__ P, float* __restrict__ S, int L, int CL) {
  __shared__ float BC[32][32];
  const int tid = threadIdx.x;
  const int d = blockIdx.x * 256 + tid;
  const int b = blockIdx.y;
  const int c = blockIdx.z;
  const int t0 = c * CL;
  if (tid < CL * 4) {
    int t = tid >> 2, j8 = (tid & 3) * 8;
    u16x8 v = *(const u16x8*)(dblb + ((size_t)b * L + t0 + t) * 64 + 32 + j8);
#pragma unroll
    for (int j = 0; j < 8; ++j) BC[t][j8 + j] = bf2f(v[j]);
  }
  float A[16], h[16], Pp[16];
#pragma unroll
  for (int j = 0; j < 4; ++j) {
    float4 a4 = *(const float4*)(Alog + d * 16 + j * 4);
    A[j * 4 + 0] = -__expf(a4.x); A[j * 4 + 1] = -__expf(a4.y);
    A[j * 4 + 2] = -__expf(a4.z); A[j * 4 + 3] = -__expf(a4.w);
  }
#pragma unroll
  for (int n = 0; n < 16; ++n) { h[n] = 0.f; Pp[n] = 1.f; }
  const unsigned short* dtp = dt + ((size_t)b * L + t0) * DINNER + d;
  const unsigned short* up  = u  + ((size_t)b * L + t0) * DINNER + d;
  __syncthreads();
  float dtv = bf2f(dtp[0]), uv = bf2f(up[0]);
  for (int t = 0; t < CL; ++t) {
    float dtn = 0.f, un = 0.f;
    if (t + 1 < CL) {
      dtn = bf2f(dtp[(size_t)(t + 1) * DINNER]);
      un  = bf2f(up[(size_t)(t + 1) * DINNER]);
    }
    float du = dtv * uv;
#pragma unroll
    for (int n = 0; n < 16; ++n) {
      float dA = __expf(dtv * A[n]);
      Pp[n] *= dA;
      h[n] = fmaf(dA, h[n], du * BC[t][n]);
    }
    dtv = dtn; uv = un;
  }
  size_t base = (size_t)c * 32768 + ((size_t)(b * 1024 + d) << 4);
#pragma unroll
  for (int j = 0; j < 4; ++j) {
    *(float4*)&P[base + j * 4] = make_float4(Pp[j*4], Pp[j*4+1], Pp[j*4+2], Pp[j*4+3]);
    *(float4*)&S[base + j * 4] = make_float4(h[j*4], h[j*4+1], h[j*4+2], h[j*4+3]);
  }
}

// pass2 with inlined chunk-prefix reduction; writes compact bf16 y.
__global__ __launch_bounds__(256) void scan_pass2(
    const unsigned short* __restrict__ dt, const unsigned short* __restrict__ dblb,
    const unsigned short* __restrict__ u, const unsigned short* __restrict__ xzb,
    const float* __restrict__ Alog, const float* __restrict__ Dsk,
    const float* __restrict__ P, const float* __restrict__ S,
    unsigned short* __restrict__ ysb, int L, int CL, int c0) {
  __shared__ float BC[32][32];
  const int tid = threadIdx.x;
  const int d = blockIdx.x * 256 + tid;
  const int b = blockIdx.y;
  const int c = blockIdx.z + c0;
  const int t0 = c * CL;
  if (tid < CL * 4) {
    int t = tid >> 2, j8 = (tid & 3) * 8;
    u16x8 v = *(const u16x8*)(dblb + ((size_t)b * L + t0 + t) * 64 + 32 + j8);
#pragma unroll
    for (int j = 0; j < 8; ++j) BC[t][j8 + j] = bf2f(v[j]);
  }
  float A[16], h[16];
#pragma unroll
  for (int j = 0; j < 4; ++j) {
    float4 a4 = *(const float4*)(Alog + d * 16 + j * 4);
    A[j * 4 + 0] = -__expf(a4.x); A[j * 4 + 1] = -__expf(a4.y);
    A[j * 4 + 2] = -__expf(a4.z); A[j * 4 + 3] = -__expf(a4.w);
  }
  // inline chunk-prefix: h = scan of (P,S) over chunks 0..c-1
#pragma unroll
  for (int n = 0; n < 16; ++n) h[n] = 0.f;
  size_t sbase = (size_t)(b * 1024 + d) << 4;
  for (int cc = 0; cc < c; ++cc) {
    size_t bb = (size_t)cc * 32768 + sbase;
#pragma unroll
    for (int j = 0; j < 4; ++j) {
      float4 p4 = *(const float4*)&P[bb + j * 4];
      float4 s4 = *(const float4*)&S[bb + j * 4];
      h[j*4+0] = fmaf(p4.x, h[j*4+0], s4.x);
      h[j*4+1] = fmaf(p4.y, h[j*4+1], s4.y);
      h[j*4+2] = fmaf(p4.z, h[j*4+2], s4.z);
      h[j*4+3] = fmaf(p4.w, h[j*4+3], s4.w);
    }
  }
  float Dv = Dsk[d];
  const unsigned short* dtp = dt + ((size_t)b * L + t0) * DINNER + d;
  const unsigned short* up  = u  + ((size_t)b * L + t0) * DINNER + d;
  const unsigned short* zp  = xzb + ((size_t)b * L + t0) * (2 * DINNER) + DINNER + d;
  unsigned short* yp = ysb + ((size_t)(b * 512) + (t0 - c0 * CL)) * DINNER + d;
  __syncthreads();
  float dtv = bf2f(dtp[0]), uv = bf2f(up[0]), zv = bf2f(zp[0]);
  for (int t = 0; t < CL; ++t) {
    float dtn = 0.f, un = 0.f, zn = 0.f;
    if (t + 1 < CL) {
      dtn = bf2f(dtp[(size_t)(t + 1) * DINNER]);
      un  = bf2f(up[(size_t)(t + 1) * DINNER]);
      zn  = bf2f(zp[(size_t)(t + 1) * (2 * DINNER)]);
    }
    float du = dtv * uv;
    float y = 0.f;
#pragma unroll
    for (int n = 0; n < 16; ++n) {
      float dA = __expf(dtv * A[n]);
      h[n] = fmaf(dA, h[n], du * BC[t][n]);
      y = fmaf(h[n], BC[t][16 + n], y);
    }
    float sig = 1.f / (1.f + __expf(-zv));
    yp[(size_t)t * DINNER] = f2bf((y + uv * Dv) * (zv * sig));
    dtv = dtn; uv = un; zv = zn;
  }
}

// ---------------- fused split-K reduce + residual + LayerNorm ----------------
// out_f32 = LN(res + epi(sum_z P, bias)); bf16 mirror to outb with row remap.
template<int NZ, int EPI>
__global__ __launch_bounds__(64) void ln_red_kernel(
    const float* __restrict__ res, const float* __restrict__ P,
    const float* __restrict__ bias, const float* __restrict__ g,
    const float* __restrict__ be, float* __restrict__ out,
    unsigned short* __restrict__ outb, int row_scale, int row_off) {
  int r = blockIdx.x;
  int b = r >> 9, t = r & 511;
  int lane = threadIdx.x;
  const float* rp = res + (size_t)r * DMODEL;
  size_t ob = ((size_t)(b * row_scale + row_off + t)) * DMODEL;
  float v[8];
  float s = 0.f, ss = 0.f;
#pragma unroll
  for (int j = 0; j < 8; ++j) {
    int col = lane + j * 64;
    float acc = 0.f;
#pragma unroll
    for (int z = 0; z < NZ; ++z) acc += P[(size_t)z * 524288 + (size_t)r * DMODEL + col];
    float bv = (EPI != 0) ? bias[col] : 0.f;
    float x = rp[col] + epi_apply<EPI>(acc, bv);
    v[j] = x; s += x; ss += x * x;
  }
#pragma unroll
  for (int o = 32; o > 0; o >>= 1) { s += __shfl_xor(s, o); ss += __shfl_xor(ss, o); }
  float m = s * (1.f / 512.f);
  float var = ss * (1.f / 512.f) - m * m;
  float rs = rsqrtf(var + 1e-6f);
#pragma unroll
  for (int j = 0; j < 8; ++j) {
    int col = lane + j * 64;
    float o2 = (v[j] - m) * rs * g[col] + be[col];
    out[(size_t)r * DMODEL + col] = o2;
    outb[ob + col] = f2bf(o2);
  }
}

// ---------------- final LayerNorm ----------------
__global__ __launch_bounds__(64) void ln_final_kernel(
    const float* __restrict__ res, const float* __restrict__ g,
    const float* __restrict__ be, float* __restrict__ out) {
  int r = blockIdx.x;
  int lane = threadIdx.x;
  const float* rp = res + (size_t)r * DMODEL;
  float v[8];
  float s = 0.f, ss = 0.f;
#pragma unroll
  for (int j = 0; j < 8; ++j) {
    float x = rp[lane + j * 64];
    v[j] = x; s += x; ss += x * x;
  }
#pragma unroll
  for (int o = 32; o > 0; o >>= 1) { s += __shfl_xor(s, o); ss += __shfl_xor(ss, o); }
  float m = s * (1.f / 512.f);
  float var = ss * (1.f / 512.f) - m * m;
  float rs = rsqrtf(var + 1e-6f);
#pragma unroll
  for (int j = 0; j < 8; ++j) {
    int c = lane + j * 64;
    out[(size_t)r * DMODEL + c] = (v[j] - m) * rs * g[c] + be[c];
  }
}

// ---------------- orchestration ----------------
extern "C" void kernel_launch(void* const* d_in, const int* in_sizes, int n_in,
                              void* d_out, int out_size, void* d_ws, size_t ws_size,
                              hipStream_t stream) {
  (void)in_sizes; (void)n_in; (void)out_size; (void)ws_size;
  const float* src      = (const float*)d_in[0];
  const int*   tgt      = (const int*)d_in[1];
  const float* emb      = (const float*)d_in[2];
  const float* in_w_s   = (const float*)d_in[3];
  const float* conv_w_s = (const float*)d_in[4];
  const float* conv_b_s = (const float*)d_in[5];
  const float* xproj_s  = (const float*)d_in[6];
  const float* dtw_s    = (const float*)d_in[7];
  const float* dtb_s    = (const float*)d_in[8];
  const float* Alog_s   = (const float*)d_in[9];
  const float* D_s      = (const float*)d_in[10];
  const float* outw_s   = (const float*)d_in[11];
  const float* in_w_c   = (const float*)d_in[12];
  const float* conv_w_c = (const float*)d_in[13];
  const float* conv_b_c = (const float*)d_in[14];
  const float* xproj_c  = (const float*)d_in[15];
  const float* dtw_c    = (const float*)d_in[16];
  const float* dtb_c    = (const float*)d_in[17];
  const float* Alog_c   = (const float*)d_in[18];
  const float* D_c      = (const float*)d_in[19];
  const float* outw_c   = (const float*)d_in[20];
  const float* ffn_w1   = (const float*)d_in[21];
  const float* ffn_b1   = (const float*)d_in[22];
  const float* ffn_w2   = (const float*)d_in[23];
  const float* ffn_b2   = (const float*)d_in[24];
  const float* ln_g     = (const float*)d_in[25];
  const float* ln_b     = (const float*)d_in[26];
  const float* fin_g    = (const float*)d_in[27];
  const float* fin_b    = (const float*)d_in[28];

  // ---- workspace layout ----
  float* ws   = (float*)d_ws;
  float* X    = ws;                   // 524288
  float* XZ   = X + 524288;           // 4194304 (out_proj / ffn2 split-K partials)
  float* SC_P = XZ + 4194304;         // 1048576 (xproj partials / scan P)
  float* SC_S = SC_P + 1048576;       // 1048576 (scan S)
  unsigned short* U = (unsigned short*)(SC_S + 1048576);
  unsigned short* Xb   = U;                   // 524288
  unsigned short* CATb = Xb + 524288;         // 1048576
  unsigned short* XCb  = CATb + 1048576;      // 2097152
  unsigned short* DBLb = XCb + 2097152;       // 131072  (M x 64)
  unsigned short* XZb  = DBLb + 131072;       // 4194304 (M x 2048)
  unsigned short* YSb  = XZb + 4194304;       // 1048576 (2,512,1024)
  unsigned short* DTb  = YSb + 1048576;       // 2097152 (M x 1024)
  unsigned short* WB   = DTb + 2097152;
  unsigned short* inwsb = WB;                 // 6291456
  unsigned short* inwcb = inwsb + 6291456;    // 6291456
  unsigned short* xpsb  = inwcb + 6291456;    // 393216
  unsigned short* xpcb  = xpsb + 393216;      // 393216
  unsigned short* dtwsb = xpcb + 393216;      // 196608
  unsigned short* dtwcb = dtwsb + 196608;     // 196608
  unsigned short* owsb  = dtwcb + 196608;     // 3145728
  unsigned short* owcb  = owsb + 3145728;     // 3145728
  unsigned short* f1b   = owcb + 3145728;     // 6291456
  unsigned short* f2b   = f1b + 6291456;      // 6291456

  cvt_all_kernel<<<15936, 256, 0, stream>>>(
      in_w_s, in_w_c, xproj_s, xproj_c, dtw_s, dtw_c, outw_s, outw_c,
      ffn_w1, ffn_w2, WB);
  embed_kernel<<<2048, 256, 0, stream>>>(tgt, emb, X, Xb);
  catsrc_kernel<<<256, 256, 0, stream>>>(src, CATb);

  for (int i = 0; i < NLAYERS; ++i) {
    // ---------- self mamba (L = 512, CL = 16, 32 chunks) ----------
    mgemmA<64, 0, false, true><<<dim3(16, 16), 256, 0, stream>>>(
        Xb, inwsb + (size_t)i * 1048576, nullptr, nullptr, XZb, 1024, 2048, 512, 512);
    conv_silu_kernel<<<4096, 256, 0, stream>>>(
        XZb, conv_w_s + (size_t)i * 4096, conv_b_s + (size_t)i * 1024, XCb, 512);
    mgemm<64, 0, true, false><<<dim3(1, 16, 8), 256, 0, stream>>>(
        XCb, xpsb + (size_t)i * 65536, nullptr, SC_P, nullptr, 1024, 64, 1024, 1024);
    xred_kernel<<<256, 256, 0, stream>>>(SC_P, DBLb, 65536);
    mgemm<32, 3, false, true><<<dim3(16, 16), 256, 0, stream>>>(
        DBLb, dtwsb + (size_t)i * 32768, dtb_s + (size_t)i * 1024, nullptr, DTb,
        1024, 1024, 32, 64);
    scan_pass1<<<dim3(4, 2, 32), 256, 0, stream>>>(
        DTb, DBLb, XCb, Alog_s + (size_t)i * 16384, SC_P, SC_S, 512, 16);
    scan_pass2<<<dim3(4, 2, 32), 256, 0, stream>>>(
        DTb, DBLb, XCb, XZb, Alog_s + (size_t)i * 16384, D_s + (size_t)i * 1024,
        SC_P, SC_S, YSb, 512, 16, 0);
    mgemmA<64, 0, true, false><<<dim3(4, 16, 4), 256, 0, stream>>>(
        YSb, owsb + (size_t)i * 524288, nullptr, XZ, nullptr, 1024, 512, 1024, 1024);
    ln_red_kernel<4, 0><<<1024, 64, 0, stream>>>(
        X, XZ, nullptr, ln_g + (size_t)(i * 3 + 0) * 512,
        ln_b + (size_t)(i * 3 + 0) * 512, X, CATb, 1024, 512);

    // ---------- cross mamba (L = 1024, CL = 32; y for last 512 t only) ----------
    mgemmA<64, 0, false, true><<<dim3(16, 32), 256, 0, stream>>>(
        CATb, inwcb + (size_t)i * 1048576, nullptr, nullptr, XZb, 2048, 2048, 512, 512);
    conv_silu_kernel<<<8192, 256, 0, stream>>>(
        XZb, conv_w_c + (size_t)i * 4096, conv_b_c + (size_t)i * 1024, XCb, 1024);
    mgemm<64, 0, true, false><<<dim3(1, 32, 8), 256, 0, stream>>>(
        XCb, xpcb + (size_t)i * 65536, nullptr, SC_P, nullptr, 2048, 64, 1024, 1024);
    xred_kernel<<<512, 256, 0, stream>>>(SC_P, DBLb, 131072);
    mgemm<32, 3, false, true><<<dim3(16, 32), 256, 0, stream>>>(
        DBLb, dtwcb + (size_t)i * 32768, dtb_c + (size_t)i * 1024, nullptr, DTb,
        2048, 1024, 32, 64);
    scan_pass1<<<dim3(4, 2, 32), 256, 0, stream>>>(
        DTb, DBLb, XCb, Alog_c + (size_t)i * 16384, SC_P, SC_S, 1024, 32);
    scan_pass2<<<dim3(4, 2, 16), 256, 0, stream>>>(
        DTb, DBLb, XCb, XZb, Alog_c + (size_t)i * 16384, D_c + (size_t)i * 1024,
        SC_P, SC_S, YSb, 1024, 32, 16);
    mgemmA<64, 0, true, false><<<dim3(4, 16, 4), 256, 0, stream>>>(
        YSb, owcb + (size_t)i * 524288, nullptr, XZ, nullptr, 1024, 512, 1024, 1024);
    ln_red_kernel<4, 0><<<1024, 64, 0, stream>>>(
        X, XZ, nullptr, ln_g + (size_t)(i * 3 + 1) * 512,
        ln_b + (size_t)(i * 3 + 1) * 512, X, Xb, 512, 0);

    // ---------- FFN ----------
    mgemmA<64, 1, false, true><<<dim3(16, 16), 256, 0, stream>>>(
        Xb, f1b + (size_t)i * 1048576, ffn_b1 + (size_t)i * 2048, nullptr, XZb,
        1024, 2048, 512, 512);
    mgemmA<64, 0, true, false><<<dim3(4, 16, 8), 256, 0, stream>>>(
        XZb, f2b + (size_t)i * 1048576, nullptr, XZ, nullptr, 1024, 512, 2048, 2048);
    ln_red_kernel<8, 2><<<1024, 64, 0, stream>>>(
        X, XZ, ffn_b2 + (size_t)i * 512, ln_g + (size_t)(i * 3 + 2) * 512,
        ln_b + (size_t)(i * 3 + 2) * 512, X, Xb, 512, 0);
  }

  ln_final_kernel<<<1024, 64, 0, stream>>>(X, fin_g, fin_b, (float*)d_out);
}